// Round 2
// baseline (3968.786 us; speedup 1.0000x reference)
//
#include <hip/hip_runtime.h>

// Nystrom attention, MI355X round 2: fp32 I/O (per reference dtype) with on-device
// dtype probe hedge; fp32-compute pipeline, bf16 internal staging.
// b=4, n=8192, dim=512, h=8, dh=64, m=256 landmarks, l=32, pinv iters=6, conv k=33.
//
// Fusion: out = attn1 @ (z @ (attn3 @ v)); attn1/attn3 never materialized.

#define N_SEQ 8192
#define DMODEL 512
#define NHEAD 8
#define DHEAD 64
#define NLAND 256
#define BH 32

typedef unsigned short u16;

__device__ __forceinline__ float bf2f(u16 u) { return __uint_as_float(((unsigned)u) << 16); }
__device__ __forceinline__ u16 f2bf(float f) {
    unsigned x = __float_as_uint(f);
    return (u16)((x + 0x7fffu + ((x >> 16) & 1u)) >> 16);
}

// ---------------- dtype probe: fp32 data read as u16 stream has ~80% insane
// bf16-exponent fields at even (low-half) indices; real bf16 N(0,1) has ~0.
__global__ void detect_kernel(const u16* __restrict__ X, unsigned* flag_out)
{
    __shared__ int cnt;
    if (threadIdx.x == 0) cnt = 0;
    __syncthreads();
    u16 u = X[threadIdx.x * 2];           // 512 u16 = 1KB: in-bounds either way
    int e = (u >> 7) & 0xFF;
    int insane = (u != 0) && (e < 90 || e > 140);
    atomicAdd(&cnt, insane);
    __syncthreads();
    if (threadIdx.x == 0) flag_out[0] = (cnt > 64) ? 1u : 0u;   // 1 = fp32
}

// ---------------- canonicalize input -> bf16 workspace copy ---------------------
__global__ __launch_bounds__(256) void convert_kernel(
    const void* __restrict__ in, u16* __restrict__ out, int n, const unsigned* __restrict__ flag)
{
    int i = blockIdx.x * 256 + threadIdx.x;
    if (i >= n) return;
    if (flag[0]) out[i] = f2bf(((const float*)in)[i]);
    else         out[i] = ((const u16*)in)[i];
}

// ---------------- QKV GEMM: [32768,512] @ [512,1536] -> q,k,v bf16 head layout ----
__global__ __launch_bounds__(256) void qkv_gemm_kernel(
    const u16* __restrict__ X, const u16* __restrict__ W,
    u16* __restrict__ Q, u16* __restrict__ K, u16* __restrict__ V)
{
    __shared__ float As[16][65];
    __shared__ float Bs[16][65];
    const int tid = threadIdx.x;
    const int tx = tid & 15, ty = tid >> 4;
    const int i0 = blockIdx.x * 64;
    const int j0 = blockIdx.y * 64;
    const int ar = tid >> 2, ak = (tid & 3) * 4;
    const int bk = tid >> 4, bj = (tid & 15) * 4;
    float acc[4][4];
#pragma unroll
    for (int u = 0; u < 4; ++u)
#pragma unroll
        for (int v = 0; v < 4; ++v) acc[u][v] = 0.f;

    for (int k0 = 0; k0 < DMODEL; k0 += 16) {
        ushort4 a4 = *(const ushort4*)(X + (size_t)(i0 + ar) * DMODEL + k0 + ak);
        As[ak + 0][ar] = bf2f(a4.x); As[ak + 1][ar] = bf2f(a4.y);
        As[ak + 2][ar] = bf2f(a4.z); As[ak + 3][ar] = bf2f(a4.w);
        ushort4 b4 = *(const ushort4*)(W + (size_t)(k0 + bk) * (3 * DMODEL) + j0 + bj);
        Bs[bk][bj + 0] = bf2f(b4.x); Bs[bk][bj + 1] = bf2f(b4.y);
        Bs[bk][bj + 2] = bf2f(b4.z); Bs[bk][bj + 3] = bf2f(b4.w);
        __syncthreads();
#pragma unroll
        for (int kk = 0; kk < 16; ++kk) {
            float a[4], b[4];
#pragma unroll
            for (int u = 0; u < 4; ++u) a[u] = As[kk][ty * 4 + u];
#pragma unroll
            for (int v = 0; v < 4; ++v) b[v] = Bs[kk][tx * 4 + v];
#pragma unroll
            for (int u = 0; u < 4; ++u)
#pragma unroll
                for (int v = 0; v < 4; ++v) acc[u][v] += a[u] * b[v];
        }
        __syncthreads();
    }
    const int which = j0 >> 9;           // 0=q 1=k 2=v (64-tile never crosses a 512 boundary)
    const int h = (j0 & 511) >> 6;
    u16* dst = (which == 0) ? Q : ((which == 1) ? K : V);
    const float scale = (which == 0) ? 0.125f : 1.f;   // d^-0.5 applied to q pre-pool
#pragma unroll
    for (int u = 0; u < 4; ++u) {
        int ig = i0 + ty * 4 + u;
        int b = ig >> 13, n = ig & (N_SEQ - 1);
        ushort4 o;
        o.x = f2bf(acc[u][0] * scale); o.y = f2bf(acc[u][1] * scale);
        o.z = f2bf(acc[u][2] * scale); o.w = f2bf(acc[u][3] * scale);
        *(ushort4*)(dst + ((size_t)(b * NHEAD + h) * N_SEQ + n) * DHEAD + tx * 4) = o;
    }
}

// ---------------- landmark pooling: mean over 32 consecutive tokens -------------
__global__ __launch_bounds__(64) void pool_kernel(
    const u16* __restrict__ Q, const u16* __restrict__ K,
    float* __restrict__ QL, float* __restrict__ KL)
{
    int m = blockIdx.x, bh = blockIdx.y, d = threadIdx.x;
    size_t base = ((size_t)bh * N_SEQ + m * 32) * DHEAD + d;
    float sq = 0.f, sk = 0.f;
#pragma unroll
    for (int i = 0; i < 32; ++i) {
        sq += bf2f(Q[base + i * DHEAD]);
        sk += bf2f(K[base + i * DHEAD]);
    }
    size_t ob = ((size_t)bh * NLAND + m) * DHEAD + d;
    QL[ob] = sq * (1.f / 32.f);
    KL[ob] = sk * (1.f / 32.f);
}

// ---------------- attn2 = softmax(q_l @ k_l^T) per row ---------------------------
__global__ __launch_bounds__(256) void attn2_kernel(
    const float* __restrict__ QL, const float* __restrict__ KL, float* __restrict__ A2)
{
    __shared__ float qrow[64];
    __shared__ float red[256];
    int i = blockIdx.x, bh = blockIdx.y, j = threadIdx.x;
    if (j < 64) qrow[j] = QL[((size_t)bh * NLAND + i) * DHEAD + j];
    __syncthreads();
    const float* kr = KL + ((size_t)bh * NLAND + j) * DHEAD;
    float lg = 0.f;
#pragma unroll
    for (int d = 0; d < 64; ++d) lg += qrow[d] * kr[d];
    red[j] = lg; __syncthreads();
    for (int s = 128; s > 0; s >>= 1) { if (j < s) red[j] = fmaxf(red[j], red[j + s]); __syncthreads(); }
    float mx = red[0]; __syncthreads();
    float p = __expf(lg - mx);
    red[j] = p; __syncthreads();
    for (int s = 128; s > 0; s >>= 1) { if (j < s) red[j] += red[j + s]; __syncthreads(); }
    float sum = red[0];
    A2[((size_t)bh * NLAND + i) * NLAND + j] = p / sum;
}

// ---------------- pinv normalizer: global max of row-sums / col-sums -------------
__global__ void init_scal_kernel(unsigned* scal) { if (threadIdx.x < 2) scal[threadIdx.x] = 0u; }

__global__ __launch_bounds__(256) void absmax_kernel(const float* __restrict__ A2, unsigned* scal)
{
    __shared__ float red[256];
    int bh = blockIdx.x, t = threadIdx.x;
    const float* Ab = A2 + (size_t)bh * 65536;
    float cs = 0.f, rs = 0.f;
    for (int j = 0; j < 256; ++j) cs += fabsf(Ab[t * 256 + j]);     // col[i] = sum_j |x[i,j]|
    for (int i = 0; i < 256; ++i) rs += fabsf(Ab[i * 256 + t]);     // row[j] = sum_i |x[i,j]|
    red[t] = cs; __syncthreads();
    for (int s = 128; s > 0; s >>= 1) { if (t < s) red[t] = fmaxf(red[t], red[t + s]); __syncthreads(); }
    if (t == 0) atomicMax(scal + 0, __float_as_uint(red[0]));
    __syncthreads();
    red[t] = rs; __syncthreads();
    for (int s = 128; s > 0; s >>= 1) { if (t < s) red[t] = fmaxf(red[t], red[t + s]); __syncthreads(); }
    if (t == 0) atomicMax(scal + 1, __float_as_uint(red[0]));
}

// ---------------- z0 = attn2^T / (cmax*rmax) ------------------------------------
__global__ __launch_bounds__(256) void z0_kernel(
    const float* __restrict__ A2, const unsigned* __restrict__ scal, float* __restrict__ Z)
{
    float inv = 1.f / (__uint_as_float(scal[0]) * __uint_as_float(scal[1]));
    size_t idx = (size_t)blockIdx.x * 256 + threadIdx.x;
    size_t bh = idx >> 16;
    int r = (int)(idx & 65535);
    int i = r >> 8, j = r & 255;
    Z[idx] = A2[(bh << 16) + (size_t)j * 256 + i] * inv;
}

// ---------------- batched GEMM (fp32), M=K=256, Nc in {64,256}, fused I-epilogues -
// mode_b=1: B' = sb*I - B.  mode_c: 0 plain, 1: sc*I - C, 2: 0.25*C
__global__ __launch_bounds__(256) void bgemm_kernel(
    const float* __restrict__ A, const float* __restrict__ B, float* __restrict__ C,
    int ldb, int ldc, long sB, long sC, int mode_b, float sb, int mode_c, float sc)
{
    __shared__ float As[16][65];
    __shared__ float Bs[16][65];
    const int tid = threadIdx.x;
    const int tx = tid & 15, ty = tid >> 4;
    const int i0 = blockIdx.x * 64, j0 = blockIdx.y * 64;
    const int bh = blockIdx.z;
    const float* Ab = A + (size_t)bh * 65536;
    const float* Bb = B + (size_t)bh * sB;
    float* Cb = C + (size_t)bh * sC;
    const int ar = tid >> 2, ak = (tid & 3) * 4;
    const int bk = tid >> 4, bj = (tid & 15) * 4;
    float acc[4][4];
#pragma unroll
    for (int u = 0; u < 4; ++u)
#pragma unroll
        for (int v = 0; v < 4; ++v) acc[u][v] = 0.f;

    for (int k0 = 0; k0 < 256; k0 += 16) {
        float4 a4 = *(const float4*)(Ab + (size_t)(i0 + ar) * 256 + k0 + ak);
        As[ak + 0][ar] = a4.x; As[ak + 1][ar] = a4.y; As[ak + 2][ar] = a4.z; As[ak + 3][ar] = a4.w;
        float4 b4 = *(const float4*)(Bb + (size_t)(k0 + bk) * ldb + j0 + bj);
        float b0 = b4.x, b1 = b4.y, b2 = b4.z, b3 = b4.w;
        if (mode_b) {
            int kg = k0 + bk;
            b0 = ((kg == j0 + bj + 0) ? sb : 0.f) - b0;
            b1 = ((kg == j0 + bj + 1) ? sb : 0.f) - b1;
            b2 = ((kg == j0 + bj + 2) ? sb : 0.f) - b2;
            b3 = ((kg == j0 + bj + 3) ? sb : 0.f) - b3;
        }
        Bs[bk][bj + 0] = b0; Bs[bk][bj + 1] = b1; Bs[bk][bj + 2] = b2; Bs[bk][bj + 3] = b3;
        __syncthreads();
#pragma unroll
        for (int kk = 0; kk < 16; ++kk) {
            float a[4], b[4];
#pragma unroll
            for (int u = 0; u < 4; ++u) a[u] = As[kk][ty * 4 + u];
#pragma unroll
            for (int v = 0; v < 4; ++v) b[v] = Bs[kk][tx * 4 + v];
#pragma unroll
            for (int u = 0; u < 4; ++u)
#pragma unroll
                for (int v = 0; v < 4; ++v) acc[u][v] += a[u] * b[v];
        }
        __syncthreads();
    }
#pragma unroll
    for (int u = 0; u < 4; ++u) {
        int ig = i0 + ty * 4 + u;
        float c[4];
#pragma unroll
        for (int v = 0; v < 4; ++v) {
            float x = acc[u][v];
            if (mode_c == 1) x = ((ig == j0 + tx * 4 + v) ? sc : 0.f) - x;
            else if (mode_c == 2) x *= 0.25f;
            c[v] = x;
        }
        *(float4*)(Cb + (size_t)ig * ldc + j0 + tx * 4) = make_float4(c[0], c[1], c[2], c[3]);
    }
}

// ---------------- attn3@v fused: online softmax over n, 16 landmark rows/block ----
__global__ __launch_bounds__(256) void attn3v_kernel(
    const float* __restrict__ QL, const u16* __restrict__ Kb,
    const u16* __restrict__ Vb, float* __restrict__ W3V)
{
    __shared__ float qs[16][64];
    __shared__ float ks[64][65];
    __shared__ float vs[64][65];
    __shared__ float ps[16][66];
    const int tid = threadIdx.x;
    const int bh = blockIdx.y;
    const int m0 = blockIdx.x * 16;
#pragma unroll
    for (int e = 0; e < 4; ++e) {
        int ii = tid + e * 256;
        int rr = ii >> 6, d = ii & 63;
        qs[rr][d] = QL[((size_t)bh * NLAND + m0 + rr) * DHEAD + d];
    }
    const int r = tid >> 4, sub = tid & 15;
    float m_run = -1e30f, l_run = 0.f;
    float acc[4] = {0.f, 0.f, 0.f, 0.f};
    const size_t kvbase = (size_t)bh * N_SEQ * DHEAD;
    __syncthreads();
    for (int nc = 0; nc < 128; ++nc) {
        int n0 = nc * 64;
#pragma unroll
        for (int e = 0; e < 4; ++e) {
            int elem = (tid + e * 256) * 4;
            int jj = elem >> 6, d0 = elem & 63;
            ushort4 k4 = *(const ushort4*)(Kb + kvbase + (size_t)(n0 + jj) * DHEAD + d0);
            ks[jj][d0 + 0] = bf2f(k4.x); ks[jj][d0 + 1] = bf2f(k4.y);
            ks[jj][d0 + 2] = bf2f(k4.z); ks[jj][d0 + 3] = bf2f(k4.w);
            ushort4 v4 = *(const ushort4*)(Vb + kvbase + (size_t)(n0 + jj) * DHEAD + d0);
            vs[jj][d0 + 0] = bf2f(v4.x); vs[jj][d0 + 1] = bf2f(v4.y);
            vs[jj][d0 + 2] = bf2f(v4.z); vs[jj][d0 + 3] = bf2f(v4.w);
        }
        __syncthreads();
        float lg[4] = {0.f, 0.f, 0.f, 0.f};
#pragma unroll
        for (int d = 0; d < 64; ++d) {
            float qv = qs[r][d];
            lg[0] += qv * ks[sub][d];
            lg[1] += qv * ks[sub + 16][d];
            lg[2] += qv * ks[sub + 32][d];
            lg[3] += qv * ks[sub + 48][d];
        }
        float cmax = fmaxf(fmaxf(lg[0], lg[1]), fmaxf(lg[2], lg[3]));
        for (int msk = 8; msk; msk >>= 1) cmax = fmaxf(cmax, __shfl_xor(cmax, msk, 16));
        float nm = fmaxf(m_run, cmax);
        float scale = __expf(m_run - nm);
        float psum = 0.f;
#pragma unroll
        for (int c = 0; c < 4; ++c) {
            float p = __expf(lg[c] - nm);
            ps[r][sub + c * 16] = p;
            psum += p;
        }
        for (int msk = 8; msk; msk >>= 1) psum += __shfl_xor(psum, msk, 16);
        l_run = l_run * scale + psum;
        m_run = nm;
        __syncthreads();
        const int d0 = sub * 4;
        float s0 = 0.f, s1 = 0.f, s2 = 0.f, s3 = 0.f;
#pragma unroll
        for (int j = 0; j < 64; ++j) {
            float p = ps[r][j];
            s0 += p * vs[j][d0 + 0]; s1 += p * vs[j][d0 + 1];
            s2 += p * vs[j][d0 + 2]; s3 += p * vs[j][d0 + 3];
        }
        acc[0] = acc[0] * scale + s0; acc[1] = acc[1] * scale + s1;
        acc[2] = acc[2] * scale + s2; acc[3] = acc[3] * scale + s3;
        __syncthreads();
    }
    float invl = 1.f / l_run;
    size_t ob = ((size_t)bh * NLAND + m0 + r) * DHEAD + sub * 4;
    W3V[ob + 0] = acc[0] * invl; W3V[ob + 1] = acc[1] * invl;
    W3V[ob + 2] = acc[2] * invl; W3V[ob + 3] = acc[3] * invl;
}

// ---------------- attn1 softmax fused with @Wmat + depthwise-conv residual -> y --
__global__ __launch_bounds__(256) void outheads_kernel(
    const u16* __restrict__ Qb, const float* __restrict__ KL,
    const float* __restrict__ WM, const u16* __restrict__ Vb,
    const u16* __restrict__ CW, u16* __restrict__ Y)
{
    __shared__ float qs[16][64];
    __shared__ float kws[64][65];     // reused: k_l chunk (phase 2) then Wmat chunk (phase 4)
    __shared__ float lgs[16][258];
    __shared__ float vsh[48][65];
    __shared__ float cws[33];
    const int tid = threadIdx.x;
    const int bh = blockIdx.y;
    const int bb = bh >> 3, h = bh & 7;
    const int n0 = blockIdx.x * 16;
    const int r = tid >> 4, sub = tid & 15;
    {
        int elem = tid * 4;
        int rr = elem >> 6, d0 = elem & 63;
        ushort4 q4 = *(const ushort4*)(Qb + ((size_t)bh * N_SEQ + n0 + rr) * DHEAD + d0);
        qs[rr][d0 + 0] = bf2f(q4.x); qs[rr][d0 + 1] = bf2f(q4.y);
        qs[rr][d0 + 2] = bf2f(q4.z); qs[rr][d0 + 3] = bf2f(q4.w);
    }
    if (tid < 33) cws[tid] = bf2f(CW[h * 33 + tid]);
    __syncthreads();
    // phase 2: logits over all 256 landmarks, in 4 chunks of 64
    for (int mc = 0; mc < 4; ++mc) {
#pragma unroll
        for (int e = 0; e < 4; ++e) {
            int elem = (tid + e * 256) * 4;
            int jj = elem >> 6, d0 = elem & 63;
            float4 k4 = *(const float4*)(KL + ((size_t)bh * NLAND + mc * 64 + jj) * DHEAD + d0);
            kws[jj][d0 + 0] = k4.x; kws[jj][d0 + 1] = k4.y;
            kws[jj][d0 + 2] = k4.z; kws[jj][d0 + 3] = k4.w;
        }
        __syncthreads();
        float lg[4] = {0.f, 0.f, 0.f, 0.f};
#pragma unroll
        for (int d = 0; d < 64; ++d) {
            float qv = qs[r][d];
            lg[0] += qv * kws[sub][d];
            lg[1] += qv * kws[sub + 16][d];
            lg[2] += qv * kws[sub + 32][d];
            lg[3] += qv * kws[sub + 48][d];
        }
        lgs[r][mc * 64 + sub] = lg[0];
        lgs[r][mc * 64 + sub + 16] = lg[1];
        lgs[r][mc * 64 + sub + 32] = lg[2];
        lgs[r][mc * 64 + sub + 48] = lg[3];
        __syncthreads();
    }
    // phase 3: row softmax over 256
    float mx = -1e30f;
    float pv[16];
#pragma unroll
    for (int c = 0; c < 16; ++c) { pv[c] = lgs[r][sub + c * 16]; mx = fmaxf(mx, pv[c]); }
    for (int msk = 8; msk; msk >>= 1) mx = fmaxf(mx, __shfl_xor(mx, msk, 16));
    float sum = 0.f;
#pragma unroll
    for (int c = 0; c < 16; ++c) {
        float p = __expf(pv[c] - mx);
        lgs[r][sub + c * 16] = p;
        sum += p;
    }
    for (int msk = 8; msk; msk >>= 1) sum += __shfl_xor(sum, msk, 16);
    float invl = 1.f / sum;
    __syncthreads();
    // phase 4: acc = P @ Wmat
    float acc[4] = {0.f, 0.f, 0.f, 0.f};
    const int d0 = sub * 4;
    for (int mc = 0; mc < 4; ++mc) {
#pragma unroll
        for (int e = 0; e < 4; ++e) {
            int elem = (tid + e * 256) * 4;
            int jj = elem >> 6, dd = elem & 63;
            float4 w4 = *(const float4*)(WM + ((size_t)bh * NLAND + mc * 64 + jj) * DHEAD + dd);
            kws[jj][dd + 0] = w4.x; kws[jj][dd + 1] = w4.y;
            kws[jj][dd + 2] = w4.z; kws[jj][dd + 3] = w4.w;
        }
        __syncthreads();
#pragma unroll
        for (int j = 0; j < 64; ++j) {
            float p = lgs[r][mc * 64 + j];
            acc[0] += p * kws[j][d0 + 0]; acc[1] += p * kws[j][d0 + 1];
            acc[2] += p * kws[j][d0 + 2]; acc[3] += p * kws[j][d0 + 3];
        }
        __syncthreads();
    }
#pragma unroll
    for (int c = 0; c < 4; ++c) acc[c] *= invl;
    // phase 5: depthwise conv residual on v (rows n0-16 .. n0+31, zero padded)
#pragma unroll
    for (int e = 0; e < 3; ++e) {
        int elem = (tid + e * 256) * 4;
        int rr = elem >> 6, dd = elem & 63;
        int gr = n0 - 16 + rr;
        float x0 = 0.f, x1 = 0.f, x2 = 0.f, x3 = 0.f;
        if (gr >= 0 && gr < N_SEQ) {
            ushort4 v4 = *(const ushort4*)(Vb + ((size_t)bh * N_SEQ + gr) * DHEAD + dd);
            x0 = bf2f(v4.x); x1 = bf2f(v4.y); x2 = bf2f(v4.z); x3 = bf2f(v4.w);
        }
        vsh[rr][dd + 0] = x0; vsh[rr][dd + 1] = x1; vsh[rr][dd + 2] = x2; vsh[rr][dd + 3] = x3;
    }
    __syncthreads();
#pragma unroll
    for (int t = 0; t < 33; ++t) {
        float w = cws[t];
        acc[0] += w * vsh[r + t][d0 + 0]; acc[1] += w * vsh[r + t][d0 + 1];
        acc[2] += w * vsh[r + t][d0 + 2]; acc[3] += w * vsh[r + t][d0 + 3];
    }
    // phase 6: write y[b, n, h*64+d] bf16
    size_t yb = ((size_t)bb * N_SEQ + n0 + r) * DMODEL + h * DHEAD + d0;
    ushort4 o;
    o.x = f2bf(acc[0]); o.y = f2bf(acc[1]); o.z = f2bf(acc[2]); o.w = f2bf(acc[3]);
    *(ushort4*)(Y + yb) = o;
}

// ---------------- final GEMM: out = x + y @ w_out + b_out (flag-gated store) ----
__global__ __launch_bounds__(256) void final_gemm_kernel(
    const u16* __restrict__ Y, const u16* __restrict__ W,
    const u16* __restrict__ Bias, const u16* __restrict__ X, void* __restrict__ Out,
    const unsigned* __restrict__ flag)
{
    __shared__ float As[16][65];
    __shared__ float Bs[16][65];
    const int tid = threadIdx.x;
    const int tx = tid & 15, ty = tid >> 4;
    const int i0 = blockIdx.x * 64;
    const int j0 = blockIdx.y * 64;
    const int ar = tid >> 2, ak = (tid & 3) * 4;
    const int bk = tid >> 4, bj = (tid & 15) * 4;
    const unsigned isf32 = flag[0];
    float acc[4][4];
#pragma unroll
    for (int u = 0; u < 4; ++u)
#pragma unroll
        for (int v = 0; v < 4; ++v) acc[u][v] = 0.f;

    for (int k0 = 0; k0 < DMODEL; k0 += 16) {
        ushort4 a4 = *(const ushort4*)(Y + (size_t)(i0 + ar) * DMODEL + k0 + ak);
        As[ak + 0][ar] = bf2f(a4.x); As[ak + 1][ar] = bf2f(a4.y);
        As[ak + 2][ar] = bf2f(a4.z); As[ak + 3][ar] = bf2f(a4.w);
        ushort4 b4 = *(const ushort4*)(W + (size_t)(k0 + bk) * DMODEL + j0 + bj);
        Bs[bk][bj + 0] = bf2f(b4.x); Bs[bk][bj + 1] = bf2f(b4.y);
        Bs[bk][bj + 2] = bf2f(b4.z); Bs[bk][bj + 3] = bf2f(b4.w);
        __syncthreads();
#pragma unroll
        for (int kk = 0; kk < 16; ++kk) {
            float a[4], b[4];
#pragma unroll
            for (int u = 0; u < 4; ++u) a[u] = As[kk][ty * 4 + u];
#pragma unroll
            for (int v = 0; v < 4; ++v) b[v] = Bs[kk][tx * 4 + v];
#pragma unroll
            for (int u = 0; u < 4; ++u)
#pragma unroll
                for (int v = 0; v < 4; ++v) acc[u][v] += a[u] * b[v];
        }
        __syncthreads();
    }
#pragma unroll
    for (int u = 0; u < 4; ++u) {
        int ig = i0 + ty * 4 + u;
        float c[4];
#pragma unroll
        for (int v = 0; v < 4; ++v) {
            int jg = j0 + tx * 4 + v;
            c[v] = acc[u][v] + bf2f(Bias[jg]) + bf2f(X[(size_t)ig * DMODEL + jg]);
        }
        if (isf32) {
            *(float4*)((float*)Out + (size_t)ig * DMODEL + j0 + tx * 4) =
                make_float4(c[0], c[1], c[2], c[3]);
        } else {
            ushort4 o;
            o.x = f2bf(c[0]); o.y = f2bf(c[1]); o.z = f2bf(c[2]); o.w = f2bf(c[3]);
            *(ushort4*)((u16*)Out + (size_t)ig * DMODEL + j0 + tx * 4) = o;
        }
    }
}

extern "C" void kernel_launch(void* const* d_in, const int* in_sizes, int n_in,
                              void* d_out, int out_size, void* d_ws, size_t ws_size,
                              hipStream_t stream)
{
    (void)in_sizes; (void)n_in; (void)out_size; (void)ws_size;
    char* ws = (char*)d_ws;
    // workspace layout (~191 MB, lifetime-overlaid; round-1's 193 MB didn't fault)
    u16*   Xc    = (u16*)(ws + 0);            // 33,554,432 B
    u16*   Wqkvc = (u16*)(ws + 33554432);     //  1,572,864 B
    u16*   Woutc = (u16*)(ws + 35127296);     //    524,288 B
    u16*   Boutc = (u16*)(ws + 35651584);     //      1,024 B
    u16*   CWc   = (u16*)(ws + 35652608);     //      1,024 B
    u16*   Qb    = (u16*)(ws + 35653632);     // 33,554,432 B
    u16*   Kb    = (u16*)(ws + 69208064);     // 33,554,432 B
    u16*   Vb    = (u16*)(ws + 102762496);    // 33,554,432 B
    float* QL    = (float*)(ws + 136316928);  //  2,097,152 B
    float* KL    = (float*)(ws + 138414080);  //  2,097,152 B
    float* A2    = (float*)(ws + 140511232);  //  8,388,608 B (dead after pinv loop)
    float* ZA    = (float*)(ws + 148899840);  //  8,388,608 B
    float* ZB    = (float*)(ws + 157288448);  //  8,388,608 B (dead after loop)
    float* XZ    = (float*)(ws + 165677056);  //  8,388,608 B (dead after loop)
    float* T2    = (float*)(ws + 174065664);  //  8,388,608 B (dead after loop)
    float* T3    = (float*)(ws + 182454272);  //  8,388,608 B (dead after loop)
    float* W3V   = (float*)(ws + 140511232);  // overlays A2 (post-loop)
    float* WM    = (float*)(ws + 142608384);  // overlays A2+2MB (post-loop)
    u16*   Yb    = (u16*)(ws + 157288448);    // overlays ZB..T3 (post-loop), 33,554,432 B
    unsigned* SCAL = (unsigned*)(ws + 190842880);  // [0..1]=pinv scale, [2]=dtype flag

    // dtype probe + canonicalize all inputs to bf16
    detect_kernel<<<1, 256, 0, stream>>>((const u16*)d_in[0], SCAL + 2);
    convert_kernel<<<65536, 256, 0, stream>>>(d_in[0], Xc,    16777216, SCAL + 2);
    convert_kernel<<<3072,  256, 0, stream>>>(d_in[1], Wqkvc,   786432, SCAL + 2);
    convert_kernel<<<1024,  256, 0, stream>>>(d_in[2], Woutc,   262144, SCAL + 2);
    convert_kernel<<<2,     256, 0, stream>>>(d_in[3], Boutc,      512, SCAL + 2);
    convert_kernel<<<2,     256, 0, stream>>>(d_in[4], CWc,        264, SCAL + 2);

    qkv_gemm_kernel<<<dim3(512, 24), 256, 0, stream>>>(Xc, Wqkvc, Qb, Kb, Vb);
    pool_kernel<<<dim3(256, BH), 64, 0, stream>>>(Qb, Kb, QL, KL);
    attn2_kernel<<<dim3(256, BH), 256, 0, stream>>>(QL, KL, A2);
    init_scal_kernel<<<1, 64, 0, stream>>>(SCAL);
    absmax_kernel<<<32, 256, 0, stream>>>(A2, SCAL);
    z0_kernel<<<8192, 256, 0, stream>>>(A2, SCAL, ZA);

    float* z = ZA; float* zn = ZB;
    for (int it = 0; it < 6; ++it) {
        // xz = attn2 @ z
        bgemm_kernel<<<dim3(4, 4, 32), 256, 0, stream>>>(A2, z, XZ, 256, 256, 65536, 65536, 0, 0.f, 0, 0.f);
        // t2 = 15I - xz @ (7I - xz)
        bgemm_kernel<<<dim3(4, 4, 32), 256, 0, stream>>>(XZ, XZ, T2, 256, 256, 65536, 65536, 1, 7.f, 1, 15.f);
        // t3 = 13I - xz @ t2
        bgemm_kernel<<<dim3(4, 4, 32), 256, 0, stream>>>(XZ, T2, T3, 256, 256, 65536, 65536, 0, 0.f, 1, 13.f);
        // z' = 0.25 * z @ t3
        bgemm_kernel<<<dim3(4, 4, 32), 256, 0, stream>>>(z, T3, zn, 256, 256, 65536, 65536, 0, 0.f, 2, 0.f);
        float* t = z; z = zn; zn = t;
    }
    // w3v = softmax(q_l k^T) @ v   (online softmax over n)
    attn3v_kernel<<<dim3(16, BH), 256, 0, stream>>>(QL, Kb, Vb, W3V);
    // Wmat = z @ w3v   (z ends in ZA after 6 swaps)
    bgemm_kernel<<<dim3(4, 1, 32), 256, 0, stream>>>(z, W3V, WM, 64, 64, 16384, 16384, 0, 0.f, 0, 0.f);
    // y = softmax(q k_l^T) @ Wmat + conv_res(v), scattered to [b,n,dim]
    outheads_kernel<<<dim3(512, BH), 256, 0, stream>>>(Qb, KL, WM, Vb, CWc, Yb);
    // out = x + y @ w_out + b_out
    final_gemm_kernel<<<dim3(512, 8), 256, 0, stream>>>(Yb, Woutc, Boutc, Xc, d_out, SCAL + 2);
}

// Round 3
// 2359.322 us; speedup vs baseline: 1.6822x; 1.6822x over previous
//
#include <hip/hip_runtime.h>

// Nystrom attention, MI355X round 3: MFMA bf16 for all straight GEMMs
// (qkv, out-proj, pinv Newton-Schulz batch); fp32 accumulate, bf16 staging.
// b=4, n=8192, dim=512, h=8, dh=64, m=256 landmarks, pinv iters=6, conv k=33.

#define N_SEQ 8192
#define DMODEL 512
#define NHEAD 8
#define DHEAD 64
#define NLAND 256
#define BH 32

typedef unsigned short u16;
typedef __attribute__((ext_vector_type(8))) short bh8;   // 8 bf16 (4 VGPRs)
typedef __attribute__((ext_vector_type(4))) float fx4;   // 4 fp32 acc

__device__ __forceinline__ float bf2f(u16 u) { return __uint_as_float(((unsigned)u) << 16); }
__device__ __forceinline__ u16 f2bf(float f) {
    unsigned x = __float_as_uint(f);
    return (u16)((x + 0x7fffu + ((x >> 16) & 1u)) >> 16);
}
__device__ __forceinline__ fx4 mfma16(bh8 a, bh8 b, fx4 c) {
    return __builtin_amdgcn_mfma_f32_16x16x32_bf16(a, b, c, 0, 0, 0);
}

// ---------------- dtype probe: fp32 data read as u16 stream has ~80% insane
// bf16-exponent fields at even (low-half) indices; real bf16 N(0,1) has ~0.
__global__ void detect_kernel(const u16* __restrict__ X, unsigned* flag_out)
{
    __shared__ int cnt;
    if (threadIdx.x == 0) cnt = 0;
    __syncthreads();
    u16 u = X[threadIdx.x * 2];
    int e = (u >> 7) & 0xFF;
    int insane = (u != 0) && (e < 90 || e > 140);
    atomicAdd(&cnt, insane);
    __syncthreads();
    if (threadIdx.x == 0) flag_out[0] = (cnt > 64) ? 1u : 0u;   // 1 = fp32
}

// ---------------- canonicalize input -> bf16 workspace copy ---------------------
__global__ __launch_bounds__(256) void convert_kernel(
    const void* __restrict__ in, u16* __restrict__ out, int n, const unsigned* __restrict__ flag)
{
    int i = blockIdx.x * 256 + threadIdx.x;
    if (i >= n) return;
    if (flag[0]) out[i] = f2bf(((const float*)in)[i]);
    else         out[i] = ((const u16*)in)[i];
}

// ---------------- transpose-convert weights: [rows][cols] -> bf16 [cols][rows] --
__global__ __launch_bounds__(256) void wtrans_kernel(
    const void* __restrict__ in, u16* __restrict__ out, int rows, int cols,
    const unsigned* __restrict__ flag)
{
    int idx = blockIdx.x * 256 + threadIdx.x;
    if (idx >= rows * cols) return;
    int r = idx / cols, c = idx % cols;
    float v = flag[0] ? ((const float*)in)[idx] : bf2f(((const u16*)in)[idx]);
    out[(size_t)c * rows + r] = f2bf(v);
}

// ---------------- fp32 -> bf16 elementwise --------------------------------------
__global__ __launch_bounds__(256) void f2b_kernel(const float* __restrict__ in, u16* __restrict__ out, int n)
{
    int i = blockIdx.x * 256 + threadIdx.x;
    if (i < n) out[i] = f2bf(in[i]);
}

// ---------------- QKV MFMA GEMM: [32768,512]@[512,1536] -> q,k,v head layout ----
// WT is w_qkv transposed: [1536 n][512 k] bf16, k-contiguous.
__global__ __launch_bounds__(256) void qkv_mfma_kernel(
    const u16* __restrict__ X, const u16* __restrict__ WT,
    u16* __restrict__ Q, u16* __restrict__ K, u16* __restrict__ V)
{
    __shared__ u16 Xs[128 * 40];    // [row m][32 k], stride 40 (16B-aligned, ~2-way)
    __shared__ u16 Ws[128 * 40];    // [row n][32 k]
    const int tid = threadIdx.x;
    const int wave = tid >> 6, lane = tid & 63;
    const int wrow = (wave >> 1) * 64, wcol = (wave & 1) * 64;   // m-off, n-off
    const int i0 = blockIdx.x * 128;   // m
    const int j0 = blockIdx.y * 128;   // n
    const int lr = tid >> 2, lk = (tid & 3) * 8;
    const int lm = lane & 15, lq = lane >> 4;
    fx4 acc[4][4];
#pragma unroll
    for (int a = 0; a < 4; ++a)
#pragma unroll
        for (int b = 0; b < 4; ++b) acc[a][b] = (fx4){0.f, 0.f, 0.f, 0.f};

    for (int k0 = 0; k0 < DMODEL; k0 += 32) {
        uint4 x0 = *(const uint4*)(X + (size_t)(i0 + lr) * DMODEL + k0 + lk);
        uint4 x1 = *(const uint4*)(X + (size_t)(i0 + 64 + lr) * DMODEL + k0 + lk);
        uint4 w0 = *(const uint4*)(WT + (size_t)(j0 + lr) * DMODEL + k0 + lk);
        uint4 w1 = *(const uint4*)(WT + (size_t)(j0 + 64 + lr) * DMODEL + k0 + lk);
        __syncthreads();
        *(uint4*)(Xs + lr * 40 + lk) = x0;
        *(uint4*)(Xs + (64 + lr) * 40 + lk) = x1;
        *(uint4*)(Ws + lr * 40 + lk) = w0;
        *(uint4*)(Ws + (64 + lr) * 40 + lk) = w1;
        __syncthreads();
        bh8 xf[4], wf[4];
#pragma unroll
        for (int im = 0; im < 4; ++im)
            xf[im] = *(const bh8*)(Xs + (wrow + im * 16 + lm) * 40 + lq * 8);
#pragma unroll
        for (int in = 0; in < 4; ++in)
            wf[in] = *(const bh8*)(Ws + (wcol + in * 16 + lm) * 40 + lq * 8);
#pragma unroll
        for (int im = 0; im < 4; ++im)
#pragma unroll
            for (int in = 0; in < 4; ++in)
                acc[im][in] = mfma16(wf[in], xf[im], acc[im][in]);  // A-op=W -> D row=n
    }
    // D layout: col=lane&15 -> m, row=lq*4+reg -> n (4 consecutive n per lane)
#pragma unroll
    for (int im = 0; im < 4; ++im) {
        int m = i0 + wrow + im * 16 + lm;
        int bb = m >> 13, ns = m & (N_SEQ - 1);
#pragma unroll
        for (int in = 0; in < 4; ++in) {
            int nn = j0 + wcol + in * 16 + (lq << 2);
            int which = nn >> 9;
            int h = (nn >> 6) & 7;
            int d = nn & 63;
            u16* dst = (which == 0) ? Q : ((which == 1) ? K : V);
            float sc = (which == 0) ? 0.125f : 1.f;
            ushort4 o;
            o.x = f2bf(acc[im][in][0] * sc); o.y = f2bf(acc[im][in][1] * sc);
            o.z = f2bf(acc[im][in][2] * sc); o.w = f2bf(acc[im][in][3] * sc);
            *(ushort4*)(dst + ((size_t)(bb * NHEAD + h) * N_SEQ + ns) * DHEAD + d) = o;
        }
    }
}

// ---------------- final MFMA GEMM: out = x + y@w_out + b_out --------------------
__global__ __launch_bounds__(256) void final_mfma_kernel(
    const u16* __restrict__ Y, const u16* __restrict__ WT,
    const u16* __restrict__ Bias, const u16* __restrict__ X, void* __restrict__ Out,
    const unsigned* __restrict__ flag)
{
    __shared__ u16 Xs[128 * 40];
    __shared__ u16 Ws[128 * 40];
    const int tid = threadIdx.x;
    const int wave = tid >> 6, lane = tid & 63;
    const int wrow = (wave >> 1) * 64, wcol = (wave & 1) * 64;
    const int i0 = blockIdx.x * 128;
    const int j0 = blockIdx.y * 128;
    const int lr = tid >> 2, lk = (tid & 3) * 8;
    const int lm = lane & 15, lq = lane >> 4;
    const unsigned isf32 = flag[0];
    fx4 acc[4][4];
#pragma unroll
    for (int a = 0; a < 4; ++a)
#pragma unroll
        for (int b = 0; b < 4; ++b) acc[a][b] = (fx4){0.f, 0.f, 0.f, 0.f};

    for (int k0 = 0; k0 < DMODEL; k0 += 32) {
        uint4 x0 = *(const uint4*)(Y + (size_t)(i0 + lr) * DMODEL + k0 + lk);
        uint4 x1 = *(const uint4*)(Y + (size_t)(i0 + 64 + lr) * DMODEL + k0 + lk);
        uint4 w0 = *(const uint4*)(WT + (size_t)(j0 + lr) * DMODEL + k0 + lk);
        uint4 w1 = *(const uint4*)(WT + (size_t)(j0 + 64 + lr) * DMODEL + k0 + lk);
        __syncthreads();
        *(uint4*)(Xs + lr * 40 + lk) = x0;
        *(uint4*)(Xs + (64 + lr) * 40 + lk) = x1;
        *(uint4*)(Ws + lr * 40 + lk) = w0;
        *(uint4*)(Ws + (64 + lr) * 40 + lk) = w1;
        __syncthreads();
        bh8 xf[4], wf[4];
#pragma unroll
        for (int im = 0; im < 4; ++im)
            xf[im] = *(const bh8*)(Xs + (wrow + im * 16 + lm) * 40 + lq * 8);
#pragma unroll
        for (int in = 0; in < 4; ++in)
            wf[in] = *(const bh8*)(Ws + (wcol + in * 16 + lm) * 40 + lq * 8);
#pragma unroll
        for (int im = 0; im < 4; ++im)
#pragma unroll
            for (int in = 0; in < 4; ++in)
                acc[im][in] = mfma16(wf[in], xf[im], acc[im][in]);
    }
#pragma unroll
    for (int im = 0; im < 4; ++im) {
        int m = i0 + wrow + im * 16 + lm;
#pragma unroll
        for (int in = 0; in < 4; ++in) {
            int nn = j0 + wcol + in * 16 + (lq << 2);
            ushort4 b4 = *(const ushort4*)(Bias + nn);
            ushort4 x4 = *(const ushort4*)(X + (size_t)m * DMODEL + nn);
            float c0 = acc[im][in][0] + bf2f(b4.x) + bf2f(x4.x);
            float c1 = acc[im][in][1] + bf2f(b4.y) + bf2f(x4.y);
            float c2 = acc[im][in][2] + bf2f(b4.z) + bf2f(x4.z);
            float c3 = acc[im][in][3] + bf2f(b4.w) + bf2f(x4.w);
            if (isf32) {
                *(float4*)((float*)Out + (size_t)m * DMODEL + nn) = make_float4(c0, c1, c2, c3);
            } else {
                ushort4 o;
                o.x = f2bf(c0); o.y = f2bf(c1); o.z = f2bf(c2); o.w = f2bf(c3);
                *(ushort4*)((u16*)Out + (size_t)m * DMODEL + nn) = o;
            }
        }
    }
}

// ---------------- batched MFMA GEMM for pinv: C = sc*I + alpha*E + beta*(A@B) ----
// A [bh][256 m][256 k] bf16 row-major; BT [bh][N n][256 k] bf16 (B transposed).
// Writes Cn [bh][256][N] (scalar, if wn) and Ct [bh][N? -> 256n][256m] (ushort4, if wt).
__global__ __launch_bounds__(256) void bgemm_mfma_kernel(
    const u16* __restrict__ A, const u16* __restrict__ BT,
    u16* __restrict__ Cn, u16* __restrict__ Ct, const u16* __restrict__ E,
    int N, long sB, long sCn, float sc, float alpha, float beta, int wn, int wt)
{
    __shared__ u16 As[64 * 40];
    __shared__ u16 Bs[64 * 40];
    const int tid = threadIdx.x;
    const int wave = tid >> 6, lane = tid & 63;
    const int wm = (wave >> 1) * 32, wnn = (wave & 1) * 32;
    const int i0 = blockIdx.x * 64, j0 = blockIdx.y * 64, bh = blockIdx.z;
    const u16* Ab = A + (size_t)bh * 65536;
    const u16* Bb = BT + (size_t)bh * sB;
    const int lr = tid >> 2, lk = (tid & 3) * 8;
    const int lm = lane & 15, lq = lane >> 4;
    fx4 acc[2][2];
#pragma unroll
    for (int a = 0; a < 2; ++a)
#pragma unroll
        for (int b = 0; b < 2; ++b) acc[a][b] = (fx4){0.f, 0.f, 0.f, 0.f};

    for (int k0 = 0; k0 < 256; k0 += 32) {
        uint4 a4 = *(const uint4*)(Ab + (size_t)(i0 + lr) * 256 + k0 + lk);
        uint4 b4 = *(const uint4*)(Bb + (size_t)(j0 + lr) * 256 + k0 + lk);
        __syncthreads();
        *(uint4*)(As + lr * 40 + lk) = a4;
        *(uint4*)(Bs + lr * 40 + lk) = b4;
        __syncthreads();
        bh8 lf[2], rf[2];
#pragma unroll
        for (int im = 0; im < 2; ++im)
            lf[im] = *(const bh8*)(As + (wm + im * 16 + lm) * 40 + lq * 8);
#pragma unroll
        for (int in = 0; in < 2; ++in)
            rf[in] = *(const bh8*)(Bs + (wnn + in * 16 + lm) * 40 + lq * 8);
#pragma unroll
        for (int im = 0; im < 2; ++im)
#pragma unroll
            for (int in = 0; in < 2; ++in)
                acc[im][in] = mfma16(lf[im], rf[in], acc[im][in]);  // A-op=left -> D row=m
    }
    // D: row=lq*4+reg -> m (consecutive), col=lane&15 -> n
#pragma unroll
    for (int im = 0; im < 2; ++im) {
#pragma unroll
        for (int in = 0; in < 2; ++in) {
            int n = j0 + wnn + in * 16 + lm;
            int m0 = i0 + wm + im * 16 + (lq << 2);
            float c[4];
#pragma unroll
            for (int r = 0; r < 4; ++r) {
                int m = m0 + r;
                float x = beta * acc[im][in][r];
                if (alpha != 0.f)
                    x += alpha * bf2f(E[(size_t)bh * 65536 + (size_t)m * 256 + n]);
                if (m == n) x += sc;
                c[r] = x;
            }
            if (wn) {
#pragma unroll
                for (int r = 0; r < 4; ++r)
                    Cn[(size_t)bh * sCn + (size_t)(m0 + r) * N + n] = f2bf(c[r]);
            }
            if (wt) {
                ushort4 o;
                o.x = f2bf(c[0]); o.y = f2bf(c[1]); o.z = f2bf(c[2]); o.w = f2bf(c[3]);
                *(ushort4*)(Ct + (size_t)bh * 65536 + (size_t)n * 256 + m0) = o;
            }
        }
    }
}

// ---------------- landmark pooling: mean over 32 consecutive tokens -------------
__global__ __launch_bounds__(64) void pool_kernel(
    const u16* __restrict__ Q, const u16* __restrict__ K,
    float* __restrict__ QL, float* __restrict__ KL)
{
    int m = blockIdx.x, bh = blockIdx.y, d = threadIdx.x;
    size_t base = ((size_t)bh * N_SEQ + m * 32) * DHEAD + d;
    float sq = 0.f, sk = 0.f;
#pragma unroll
    for (int i = 0; i < 32; ++i) {
        sq += bf2f(Q[base + i * DHEAD]);
        sk += bf2f(K[base + i * DHEAD]);
    }
    size_t ob = ((size_t)bh * NLAND + m) * DHEAD + d;
    QL[ob] = sq * (1.f / 32.f);
    KL[ob] = sk * (1.f / 32.f);
}

// ---------------- attn2 = softmax(q_l @ k_l^T) per row ---------------------------
__global__ __launch_bounds__(256) void attn2_kernel(
    const float* __restrict__ QL, const float* __restrict__ KL, float* __restrict__ A2)
{
    __shared__ float qrow[64];
    __shared__ float red[256];
    int i = blockIdx.x, bh = blockIdx.y, j = threadIdx.x;
    if (j < 64) qrow[j] = QL[((size_t)bh * NLAND + i) * DHEAD + j];
    __syncthreads();
    const float* kr = KL + ((size_t)bh * NLAND + j) * DHEAD;
    float lg = 0.f;
#pragma unroll
    for (int d = 0; d < 64; ++d) lg += qrow[d] * kr[d];
    red[j] = lg; __syncthreads();
    for (int s = 128; s > 0; s >>= 1) { if (j < s) red[j] = fmaxf(red[j], red[j + s]); __syncthreads(); }
    float mx = red[0]; __syncthreads();
    float p = __expf(lg - mx);
    red[j] = p; __syncthreads();
    for (int s = 128; s > 0; s >>= 1) { if (j < s) red[j] += red[j + s]; __syncthreads(); }
    float sum = red[0];
    A2[((size_t)bh * NLAND + i) * NLAND + j] = p / sum;
}

// ---------------- pinv normalizer: global max of row-sums / col-sums -------------
__global__ void init_scal_kernel(unsigned* scal) { if (threadIdx.x < 2) scal[threadIdx.x] = 0u; }

__global__ __launch_bounds__(256) void absmax_kernel(const float* __restrict__ A2, unsigned* scal)
{
    __shared__ float red[256];
    int bh = blockIdx.x, t = threadIdx.x;
    const float* Ab = A2 + (size_t)bh * 65536;
    float cs = 0.f, rs = 0.f;
    for (int j = 0; j < 256; ++j) cs += fabsf(Ab[t * 256 + j]);
    for (int i = 0; i < 256; ++i) rs += fabsf(Ab[i * 256 + t]);
    red[t] = cs; __syncthreads();
    for (int s = 128; s > 0; s >>= 1) { if (t < s) red[t] = fmaxf(red[t], red[t + s]); __syncthreads(); }
    if (t == 0) atomicMax(scal + 0, __float_as_uint(red[0]));
    __syncthreads();
    red[t] = rs; __syncthreads();
    for (int s = 128; s > 0; s >>= 1) { if (t < s) red[t] = fmaxf(red[t], red[t + s]); __syncthreads(); }
    if (t == 0) atomicMax(scal + 1, __float_as_uint(red[0]));
}

// ---------------- z0 (bf16, normal + transposed): z0 = attn2^T / (cmax*rmax) ----
__global__ __launch_bounds__(256) void z0_kernel(
    const float* __restrict__ A2, const unsigned* __restrict__ scal,
    u16* __restrict__ zb, u16* __restrict__ zbT)
{
    float inv = 1.f / (__uint_as_float(scal[0]) * __uint_as_float(scal[1]));
    size_t idx = (size_t)blockIdx.x * 256 + threadIdx.x;
    size_t bh = idx >> 16;
    int r = (int)(idx & 65535);
    int i = r >> 8, j = r & 255;
    zb[idx]  = f2bf(A2[(bh << 16) + (size_t)j * 256 + i] * inv);  // z0 = A2^T * inv
    zbT[idx] = f2bf(A2[idx] * inv);                               // z0^T = A2 * inv
}

// ---------------- attn3@v fused: online softmax over n -> W3V^T [bh][64 d][256 m] -
__global__ __launch_bounds__(256) void attn3v_kernel(
    const float* __restrict__ QL, const u16* __restrict__ Kb,
    const u16* __restrict__ Vb, u16* __restrict__ W3VT)
{
    __shared__ float qs[16][64];
    __shared__ float ks[64][65];
    __shared__ float vs[64][65];
    __shared__ float ps[16][66];
    const int tid = threadIdx.x;
    const int bh = blockIdx.y;
    const int m0 = blockIdx.x * 16;
#pragma unroll
    for (int e = 0; e < 4; ++e) {
        int ii = tid + e * 256;
        int rr = ii >> 6, d = ii & 63;
        qs[rr][d] = QL[((size_t)bh * NLAND + m0 + rr) * DHEAD + d];
    }
    const int r = tid >> 4, sub = tid & 15;
    float m_run = -1e30f, l_run = 0.f;
    float acc[4] = {0.f, 0.f, 0.f, 0.f};
    const size_t kvbase = (size_t)bh * N_SEQ * DHEAD;
    __syncthreads();
    for (int nc = 0; nc < 128; ++nc) {
        int n0 = nc * 64;
#pragma unroll
        for (int e = 0; e < 4; ++e) {
            int elem = (tid + e * 256) * 4;
            int jj = elem >> 6, d0 = elem & 63;
            ushort4 k4 = *(const ushort4*)(Kb + kvbase + (size_t)(n0 + jj) * DHEAD + d0);
            ks[jj][d0 + 0] = bf2f(k4.x); ks[jj][d0 + 1] = bf2f(k4.y);
            ks[jj][d0 + 2] = bf2f(k4.z); ks[jj][d0 + 3] = bf2f(k4.w);
            ushort4 v4 = *(const ushort4*)(Vb + kvbase + (size_t)(n0 + jj) * DHEAD + d0);
            vs[jj][d0 + 0] = bf2f(v4.x); vs[jj][d0 + 1] = bf2f(v4.y);
            vs[jj][d0 + 2] = bf2f(v4.z); vs[jj][d0 + 3] = bf2f(v4.w);
        }
        __syncthreads();
        float lg[4] = {0.f, 0.f, 0.f, 0.f};
#pragma unroll
        for (int d = 0; d < 64; ++d) {
            float qv = qs[r][d];
            lg[0] += qv * ks[sub][d];
            lg[1] += qv * ks[sub + 16][d];
            lg[2] += qv * ks[sub + 32][d];
            lg[3] += qv * ks[sub + 48][d];
        }
        float cmax = fmaxf(fmaxf(lg[0], lg[1]), fmaxf(lg[2], lg[3]));
        for (int msk = 8; msk; msk >>= 1) cmax = fmaxf(cmax, __shfl_xor(cmax, msk, 16));
        float nm = fmaxf(m_run, cmax);
        float scale = __expf(m_run - nm);
        float psum = 0.f;
#pragma unroll
        for (int c = 0; c < 4; ++c) {
            float p = __expf(lg[c] - nm);
            ps[r][sub + c * 16] = p;
            psum += p;
        }
        for (int msk = 8; msk; msk >>= 1) psum += __shfl_xor(psum, msk, 16);
        l_run = l_run * scale + psum;
        m_run = nm;
        __syncthreads();
        const int d0 = sub * 4;
        float s0 = 0.f, s1 = 0.f, s2 = 0.f, s3 = 0.f;
#pragma unroll
        for (int j = 0; j < 64; ++j) {
            float p = ps[r][j];
            s0 += p * vs[j][d0 + 0]; s1 += p * vs[j][d0 + 1];
            s2 += p * vs[j][d0 + 2]; s3 += p * vs[j][d0 + 3];
        }
        acc[0] = acc[0] * scale + s0; acc[1] = acc[1] * scale + s1;
        acc[2] = acc[2] * scale + s2; acc[3] = acc[3] * scale + s3;
        __syncthreads();
    }
    float invl = 1.f / l_run;
    size_t tb = (size_t)bh * (64 * NLAND);
    int mrow = m0 + r;
#pragma unroll
    for (int c = 0; c < 4; ++c)
        W3VT[tb + (size_t)(sub * 4 + c) * NLAND + mrow] = f2bf(acc[c] * invl);
}

// ---------------- attn1 softmax fused with @Wmat + depthwise-conv residual -> y --
__global__ __launch_bounds__(256) void outheads_kernel(
    const u16* __restrict__ Qb, const float* __restrict__ KL,
    const u16* __restrict__ WMb, const u16* __restrict__ Vb,
    const u16* __restrict__ CW, u16* __restrict__ Y)
{
    __shared__ float qs[16][64];
    __shared__ float kws[64][65];
    __shared__ float lgs[16][258];
    __shared__ float vsh[48][65];
    __shared__ float cws[33];
    const int tid = threadIdx.x;
    const int bh = blockIdx.y;
    const int bb = bh >> 3, h = bh & 7;
    const int n0 = blockIdx.x * 16;
    const int r = tid >> 4, sub = tid & 15;
    {
        int elem = tid * 4;
        int rr = elem >> 6, d0 = elem & 63;
        ushort4 q4 = *(const ushort4*)(Qb + ((size_t)bh * N_SEQ + n0 + rr) * DHEAD + d0);
        qs[rr][d0 + 0] = bf2f(q4.x); qs[rr][d0 + 1] = bf2f(q4.y);
        qs[rr][d0 + 2] = bf2f(q4.z); qs[rr][d0 + 3] = bf2f(q4.w);
    }
    if (tid < 33) cws[tid] = bf2f(CW[h * 33 + tid]);
    __syncthreads();
    for (int mc = 0; mc < 4; ++mc) {
#pragma unroll
        for (int e = 0; e < 4; ++e) {
            int elem = (tid + e * 256) * 4;
            int jj = elem >> 6, d0 = elem & 63;
            float4 k4 = *(const float4*)(KL + ((size_t)bh * NLAND + mc * 64 + jj) * DHEAD + d0);
            kws[jj][d0 + 0] = k4.x; kws[jj][d0 + 1] = k4.y;
            kws[jj][d0 + 2] = k4.z; kws[jj][d0 + 3] = k4.w;
        }
        __syncthreads();
        float lg[4] = {0.f, 0.f, 0.f, 0.f};
#pragma unroll
        for (int d = 0; d < 64; ++d) {
            float qv = qs[r][d];
            lg[0] += qv * kws[sub][d];
            lg[1] += qv * kws[sub + 16][d];
            lg[2] += qv * kws[sub + 32][d];
            lg[3] += qv * kws[sub + 48][d];
        }
        lgs[r][mc * 64 + sub] = lg[0];
        lgs[r][mc * 64 + sub + 16] = lg[1];
        lgs[r][mc * 64 + sub + 32] = lg[2];
        lgs[r][mc * 64 + sub + 48] = lg[3];
        __syncthreads();
    }
    float mx = -1e30f;
    float pv[16];
#pragma unroll
    for (int c = 0; c < 16; ++c) { pv[c] = lgs[r][sub + c * 16]; mx = fmaxf(mx, pv[c]); }
    for (int msk = 8; msk; msk >>= 1) mx = fmaxf(mx, __shfl_xor(mx, msk, 16));
    float sum = 0.f;
#pragma unroll
    for (int c = 0; c < 16; ++c) {
        float p = __expf(pv[c] - mx);
        lgs[r][sub + c * 16] = p;
        sum += p;
    }
    for (int msk = 8; msk; msk >>= 1) sum += __shfl_xor(sum, msk, 16);
    float invl = 1.f / sum;
    __syncthreads();
    float acc[4] = {0.f, 0.f, 0.f, 0.f};
    const int d0 = sub * 4;
    for (int mc = 0; mc < 4; ++mc) {
#pragma unroll
        for (int e = 0; e < 4; ++e) {
            int elem = (tid + e * 256) * 4;
            int jj = elem >> 6, dd = elem & 63;
            ushort4 w4 = *(const ushort4*)(WMb + ((size_t)bh * NLAND + mc * 64 + jj) * DHEAD + dd);
            kws[jj][dd + 0] = bf2f(w4.x); kws[jj][dd + 1] = bf2f(w4.y);
            kws[jj][dd + 2] = bf2f(w4.z); kws[jj][dd + 3] = bf2f(w4.w);
        }
        __syncthreads();
#pragma unroll
        for (int j = 0; j < 64; ++j) {
            float p = lgs[r][mc * 64 + j];
            acc[0] += p * kws[j][d0 + 0]; acc[1] += p * kws[j][d0 + 1];
            acc[2] += p * kws[j][d0 + 2]; acc[3] += p * kws[j][d0 + 3];
        }
        __syncthreads();
    }
#pragma unroll
    for (int c = 0; c < 4; ++c) acc[c] *= invl;
#pragma unroll
    for (int e = 0; e < 3; ++e) {
        int elem = (tid + e * 256) * 4;
        int rr = elem >> 6, dd = elem & 63;
        int gr = n0 - 16 + rr;
        float x0 = 0.f, x1 = 0.f, x2 = 0.f, x3 = 0.f;
        if (gr >= 0 && gr < N_SEQ) {
            ushort4 v4 = *(const ushort4*)(Vb + ((size_t)bh * N_SEQ + gr) * DHEAD + dd);
            x0 = bf2f(v4.x); x1 = bf2f(v4.y); x2 = bf2f(v4.z); x3 = bf2f(v4.w);
        }
        vsh[rr][dd + 0] = x0; vsh[rr][dd + 1] = x1; vsh[rr][dd + 2] = x2; vsh[rr][dd + 3] = x3;
    }
    __syncthreads();
#pragma unroll
    for (int t = 0; t < 33; ++t) {
        float w = cws[t];
        acc[0] += w * vsh[r + t][d0 + 0]; acc[1] += w * vsh[r + t][d0 + 1];
        acc[2] += w * vsh[r + t][d0 + 2]; acc[3] += w * vsh[r + t][d0 + 3];
    }
    size_t yb = ((size_t)bb * N_SEQ + n0 + r) * DMODEL + h * DHEAD + d0;
    ushort4 o;
    o.x = f2bf(acc[0]); o.y = f2bf(acc[1]); o.z = f2bf(acc[2]); o.w = f2bf(acc[3]);
    *(ushort4*)(Y + yb) = o;
}

extern "C" void kernel_launch(void* const* d_in, const int* in_sizes, int n_in,
                              void* d_out, int out_size, void* d_ws, size_t ws_size,
                              hipStream_t stream)
{
    (void)in_sizes; (void)n_in; (void)out_size; (void)ws_size;
    char* ws = (char*)d_ws;
    // workspace layout (~189 MB; round-2's 191 MB worked)
    u16*   Xc    = (u16*)(ws + 0);            // 33,554,432
    u16*   WqkvT = (u16*)(ws + 33554432);     //  1,572,864  [1536][512]
    u16*   WoutT = (u16*)(ws + 35127296);     //    524,288  [512][512]
    u16*   Boutc = (u16*)(ws + 35651584);     //      1,024
    u16*   CWc   = (u16*)(ws + 35652608);     //      1,024
    u16*   Qb    = (u16*)(ws + 35653632);     // 33,554,432
    u16*   Kb    = (u16*)(ws + 69208064);     // 33,554,432
    u16*   Vb    = (u16*)(ws + 102762496);    // 33,554,432
    float* QL    = (float*)(ws + 136316928);  //  2,097,152
    float* KL    = (float*)(ws + 138414080);  //  2,097,152
    u16*   A2b   = (u16*)(ws + 140511232);    //  4,194,304
    u16*   zA    = (u16*)(ws + 144705536);    //  4,194,304
    u16*   zAT   = (u16*)(ws + 148899840);    //  4,194,304
    u16*   W3VT  = (u16*)(ws + 153094144);    //  1,048,576  [bh][64][256]
    u16*   WMb   = (u16*)(ws + 154142720);    //  1,048,576  [bh][256][64]
    // overlay region (dead after pinv loop) -> reused as Yb
    float* A2    = (float*)(ws + 155191296);  //  8,388,608
    u16*   zB    = (u16*)(ws + 163579904);    //  4,194,304
    u16*   zBT   = (u16*)(ws + 167774208);    //  4,194,304
    u16*   xz    = (u16*)(ws + 171968512);    //  4,194,304
    u16*   xzT   = (u16*)(ws + 176162816);    //  4,194,304
    u16*   t2T   = (u16*)(ws + 180357120);    //  4,194,304
    u16*   t3T   = (u16*)(ws + 184551424);    //  4,194,304
    u16*   Yb    = (u16*)(ws + 155191296);    // 33,554,432 overlays A2..t3T
    unsigned* SCAL = (unsigned*)(ws + 188745728);

    // dtype probe + canonicalize inputs (weights transposed for MFMA B^T layout)
    detect_kernel<<<1, 256, 0, stream>>>((const u16*)d_in[0], SCAL + 2);
    convert_kernel<<<65536, 256, 0, stream>>>(d_in[0], Xc, 16777216, SCAL + 2);
    wtrans_kernel<<<3072, 256, 0, stream>>>(d_in[1], WqkvT, 512, 1536, SCAL + 2);
    wtrans_kernel<<<1024, 256, 0, stream>>>(d_in[2], WoutT, 512, 512, SCAL + 2);
    convert_kernel<<<2, 256, 0, stream>>>(d_in[3], Boutc, 512, SCAL + 2);
    convert_kernel<<<2, 256, 0, stream>>>(d_in[4], CWc, 264, SCAL + 2);

    qkv_mfma_kernel<<<dim3(256, 12), 256, 0, stream>>>(Xc, WqkvT, Qb, Kb, Vb);
    pool_kernel<<<dim3(256, BH), 64, 0, stream>>>(Qb, Kb, QL, KL);
    attn2_kernel<<<dim3(256, BH), 256, 0, stream>>>(QL, KL, A2);
    init_scal_kernel<<<1, 64, 0, stream>>>(SCAL);
    absmax_kernel<<<32, 256, 0, stream>>>(A2, SCAL);
    z0_kernel<<<8192, 256, 0, stream>>>(A2, SCAL, zA, zAT);
    f2b_kernel<<<8192, 256, 0, stream>>>(A2, A2b, 2097152);

    u16 *z = zA, *zT = zAT, *zn = zB, *znT = zBT;
    for (int it = 0; it < 6; ++it) {
        // xz = A2 @ z (dual write)
        bgemm_mfma_kernel<<<dim3(4, 4, 32), 256, 0, stream>>>(
            A2b, zT, xz, xzT, A2b, 256, 65536, 65536, 0.f, 0.f, 1.f, 1, 1);
        // t2 = 15I - 7*xz + xz@xz (transposed only)
        bgemm_mfma_kernel<<<dim3(4, 4, 32), 256, 0, stream>>>(
            xz, xzT, xz, t2T, xz, 256, 65536, 65536, 15.f, -7.f, 1.f, 0, 1);
        // t3 = 13I - xz@t2 (transposed only)
        bgemm_mfma_kernel<<<dim3(4, 4, 32), 256, 0, stream>>>(
            xz, t2T, xz, t3T, xz, 256, 65536, 65536, 13.f, 0.f, -1.f, 0, 1);
        // zn = 0.25 * z@t3 (dual write)
        bgemm_mfma_kernel<<<dim3(4, 4, 32), 256, 0, stream>>>(
            z, t3T, zn, znT, xz, 256, 65536, 65536, 0.f, 0.f, 0.25f, 1, 1);
        u16* t;
        t = z; z = zn; zn = t;
        t = zT; zT = znT; znT = t;
    }
    // w3v^T = (softmax(q_l k^T) @ v)^T  (online softmax over n)
    attn3v_kernel<<<dim3(16, BH), 256, 0, stream>>>(QL, Kb, Vb, W3VT);
    // WM = z @ w3v   [bh][256][64]
    bgemm_mfma_kernel<<<dim3(4, 1, 32), 256, 0, stream>>>(
        z, W3VT, WMb, xzT, xz, 64, 16384, 16384, 0.f, 0.f, 1.f, 1, 0);
    // y = softmax(q k_l^T) @ WM + conv_res(v)
    outheads_kernel<<<dim3(512, BH), 256, 0, stream>>>(Qb, KL, WMb, Vb, CWc, Yb);
    // out = x + y @ w_out + b_out
    final_mfma_kernel<<<dim3(256, 4), 256, 0, stream>>>(Yb, WoutT, Boutc, Xc, d_out, SCAL + 2);
}

// Round 4
// 847.494 us; speedup vs baseline: 4.6830x; 2.7839x over previous
//
#include <hip/hip_runtime.h>

// Nystrom attention, MI355X round 4: MFMA everywhere (qkv, pinv batch, attn3v
// flash, outheads, out-proj). fp32 accumulate, bf16 staging.
// b=4, n=8192, dim=512, h=8, dh=64, m=256 landmarks, pinv iters=6, conv k=33.
//
// MFMA rule (validated r3): mfma16(a,b) -> D[a_row][b_row]; fragment = 8 contig
// k at row lane&15; D: b_row=lane&15, a_row=quad*4+reg.

#define N_SEQ 8192
#define DMODEL 512
#define NHEAD 8
#define DHEAD 64
#define NLAND 256
#define BH 32

typedef unsigned short u16;
typedef __attribute__((ext_vector_type(8))) short bh8;
typedef __attribute__((ext_vector_type(4))) float fx4;

__device__ __forceinline__ float bf2f(u16 u) { return __uint_as_float(((unsigned)u) << 16); }
__device__ __forceinline__ u16 f2bf(float f) {
    unsigned x = __float_as_uint(f);
    return (u16)((x + 0x7fffu + ((x >> 16) & 1u)) >> 16);
}
__device__ __forceinline__ fx4 mfma16(bh8 a, bh8 b, fx4 c) {
    return __builtin_amdgcn_mfma_f32_16x16x32_bf16(a, b, c, 0, 0, 0);
}

// ---------------- dtype probe -----------------------------------------------------
__global__ void detect_kernel(const u16* __restrict__ X, unsigned* flag_out)
{
    __shared__ int cnt;
    if (threadIdx.x == 0) cnt = 0;
    __syncthreads();
    u16 u = X[threadIdx.x * 2];
    int e = (u >> 7) & 0xFF;
    int insane = (u != 0) && (e < 90 || e > 140);
    atomicAdd(&cnt, insane);
    __syncthreads();
    if (threadIdx.x == 0) flag_out[0] = (cnt > 64) ? 1u : 0u;
}

__global__ __launch_bounds__(256) void convert_kernel(
    const void* __restrict__ in, u16* __restrict__ out, int n, const unsigned* __restrict__ flag)
{
    int i = blockIdx.x * 256 + threadIdx.x;
    if (i >= n) return;
    if (flag[0]) out[i] = f2bf(((const float*)in)[i]);
    else         out[i] = ((const u16*)in)[i];
}

__global__ __launch_bounds__(256) void wtrans_kernel(
    const void* __restrict__ in, u16* __restrict__ out, int rows, int cols,
    const unsigned* __restrict__ flag)
{
    int idx = blockIdx.x * 256 + threadIdx.x;
    if (idx >= rows * cols) return;
    int r = idx / cols, c = idx % cols;
    float v = flag[0] ? ((const float*)in)[idx] : bf2f(((const u16*)in)[idx]);
    out[(size_t)c * rows + r] = f2bf(v);
}

__global__ __launch_bounds__(256) void f2b_kernel(const float* __restrict__ in, u16* __restrict__ out, int n)
{
    int i = blockIdx.x * 256 + threadIdx.x;
    if (i < n) out[i] = f2bf(in[i]);
}

// ---------------- QKV MFMA GEMM -> Q[n][d], K[n][d], VT[d][n] ---------------------
__global__ __launch_bounds__(256) void qkv_mfma_kernel(
    const u16* __restrict__ X, const u16* __restrict__ WT,
    u16* __restrict__ Q, u16* __restrict__ K, u16* __restrict__ VT)
{
    __shared__ u16 Xs[128 * 40];
    __shared__ u16 Ws[128 * 40];
    const int tid = threadIdx.x;
    const int wave = tid >> 6, lane = tid & 63;
    const int wrow = (wave >> 1) * 64, wcol = (wave & 1) * 64;
    const int i0 = blockIdx.x * 128;
    const int j0 = blockIdx.y * 128;
    const int lr = tid >> 2, lk = (tid & 3) * 8;
    const int lm = lane & 15, lq = lane >> 4;
    fx4 acc[4][4];
#pragma unroll
    for (int a = 0; a < 4; ++a)
#pragma unroll
        for (int b = 0; b < 4; ++b) acc[a][b] = (fx4){0.f, 0.f, 0.f, 0.f};

    for (int k0 = 0; k0 < DMODEL; k0 += 32) {
        uint4 x0 = *(const uint4*)(X + (size_t)(i0 + lr) * DMODEL + k0 + lk);
        uint4 x1 = *(const uint4*)(X + (size_t)(i0 + 64 + lr) * DMODEL + k0 + lk);
        uint4 w0 = *(const uint4*)(WT + (size_t)(j0 + lr) * DMODEL + k0 + lk);
        uint4 w1 = *(const uint4*)(WT + (size_t)(j0 + 64 + lr) * DMODEL + k0 + lk);
        __syncthreads();
        *(uint4*)(Xs + lr * 40 + lk) = x0;
        *(uint4*)(Xs + (64 + lr) * 40 + lk) = x1;
        *(uint4*)(Ws + lr * 40 + lk) = w0;
        *(uint4*)(Ws + (64 + lr) * 40 + lk) = w1;
        __syncthreads();
        bh8 xf[4], wf[4];
#pragma unroll
        for (int im = 0; im < 4; ++im)
            xf[im] = *(const bh8*)(Xs + (wrow + im * 16 + lm) * 40 + lq * 8);
#pragma unroll
        for (int in = 0; in < 4; ++in)
            wf[in] = *(const bh8*)(Ws + (wcol + in * 16 + lm) * 40 + lq * 8);
#pragma unroll
        for (int im = 0; im < 4; ++im)
#pragma unroll
            for (int in = 0; in < 4; ++in)
                acc[im][in] = mfma16(wf[in], xf[im], acc[im][in]);
    }
#pragma unroll
    for (int im = 0; im < 4; ++im) {
        int m = i0 + wrow + im * 16 + lm;
        int bb = m >> 13, ns = m & (N_SEQ - 1);
#pragma unroll
        for (int in = 0; in < 4; ++in) {
            int nn = j0 + wcol + in * 16 + (lq << 2);
            int which = nn >> 9;
            int h = (nn >> 6) & 7;
            int d = nn & 63;
            if (which == 2) {
                size_t vb = (size_t)(bb * NHEAD + h) * DHEAD;
#pragma unroll
                for (int cc = 0; cc < 4; ++cc)
                    VT[(vb + d + cc) * N_SEQ + ns] = f2bf(acc[im][in][cc]);
            } else {
                u16* dst = (which == 0) ? Q : K;
                float sc = (which == 0) ? 0.125f : 1.f;
                ushort4 o;
                o.x = f2bf(acc[im][in][0] * sc); o.y = f2bf(acc[im][in][1] * sc);
                o.z = f2bf(acc[im][in][2] * sc); o.w = f2bf(acc[im][in][3] * sc);
                *(ushort4*)(dst + ((size_t)(bb * NHEAD + h) * N_SEQ + ns) * DHEAD + d) = o;
            }
        }
    }
}

// ---------------- landmark pooling (fp32 + bf16 outputs) --------------------------
__global__ __launch_bounds__(64) void pool_kernel(
    const u16* __restrict__ Q, const u16* __restrict__ K,
    float* __restrict__ QL, float* __restrict__ KL,
    u16* __restrict__ QLb, u16* __restrict__ KLb)
{
    int m = blockIdx.x, bh = blockIdx.y, d = threadIdx.x;
    size_t base = ((size_t)bh * N_SEQ + m * 32) * DHEAD + d;
    float sq = 0.f, sk = 0.f;
#pragma unroll
    for (int i = 0; i < 32; ++i) {
        sq += bf2f(Q[base + i * DHEAD]);
        sk += bf2f(K[base + i * DHEAD]);
    }
    size_t ob = ((size_t)bh * NLAND + m) * DHEAD + d;
    sq *= (1.f / 32.f); sk *= (1.f / 32.f);
    QL[ob] = sq; KL[ob] = sk;
    QLb[ob] = f2bf(sq); KLb[ob] = f2bf(sk);
}

// ---------------- attn2 = softmax(q_l @ k_l^T) ------------------------------------
__global__ __launch_bounds__(256) void attn2_kernel(
    const float* __restrict__ QL, const float* __restrict__ KL, float* __restrict__ A2)
{
    __shared__ float qrow[64];
    __shared__ float red[256];
    int i = blockIdx.x, bh = blockIdx.y, j = threadIdx.x;
    if (j < 64) qrow[j] = QL[((size_t)bh * NLAND + i) * DHEAD + j];
    __syncthreads();
    const float* kr = KL + ((size_t)bh * NLAND + j) * DHEAD;
    float lg = 0.f;
#pragma unroll
    for (int d = 0; d < 64; ++d) lg += qrow[d] * kr[d];
    red[j] = lg; __syncthreads();
    for (int s = 128; s > 0; s >>= 1) { if (j < s) red[j] = fmaxf(red[j], red[j + s]); __syncthreads(); }
    float mx = red[0]; __syncthreads();
    float p = __expf(lg - mx);
    red[j] = p; __syncthreads();
    for (int s = 128; s > 0; s >>= 1) { if (j < s) red[j] += red[j + s]; __syncthreads(); }
    float sum = red[0];
    A2[((size_t)bh * NLAND + i) * NLAND + j] = p / sum;
}

__global__ void init_scal_kernel(unsigned* scal) { if (threadIdx.x < 2) scal[threadIdx.x] = 0u; }

__global__ __launch_bounds__(256) void absmax_kernel(const float* __restrict__ A2, unsigned* scal)
{
    __shared__ float red[256];
    int bh = blockIdx.x, t = threadIdx.x;
    const float* Ab = A2 + (size_t)bh * 65536;
    float cs = 0.f, rs = 0.f;
    for (int j = 0; j < 256; ++j) cs += fabsf(Ab[t * 256 + j]);
    for (int i = 0; i < 256; ++i) rs += fabsf(Ab[i * 256 + t]);
    red[t] = cs; __syncthreads();
    for (int s = 128; s > 0; s >>= 1) { if (t < s) red[t] = fmaxf(red[t], red[t + s]); __syncthreads(); }
    if (t == 0) atomicMax(scal + 0, __float_as_uint(red[0]));
    __syncthreads();
    red[t] = rs; __syncthreads();
    for (int s = 128; s > 0; s >>= 1) { if (t < s) red[t] = fmaxf(red[t], red[t + s]); __syncthreads(); }
    if (t == 0) atomicMax(scal + 1, __float_as_uint(red[0]));
}

__global__ __launch_bounds__(256) void z0_kernel(
    const float* __restrict__ A2, const unsigned* __restrict__ scal,
    u16* __restrict__ zb, u16* __restrict__ zbT)
{
    float inv = 1.f / (__uint_as_float(scal[0]) * __uint_as_float(scal[1]));
    size_t idx = (size_t)blockIdx.x * 256 + threadIdx.x;
    size_t bh = idx >> 16;
    int r = (int)(idx & 65535);
    int i = r >> 8, j = r & 255;
    zb[idx]  = f2bf(A2[(bh << 16) + (size_t)j * 256 + i] * inv);
    zbT[idx] = f2bf(A2[idx] * inv);
}

// ---------------- batched MFMA GEMM for pinv: C = sc*I + alpha*E + beta*(A@B) -----
__global__ __launch_bounds__(256) void bgemm_mfma_kernel(
    const u16* __restrict__ A, const u16* __restrict__ BT,
    u16* __restrict__ Cn, u16* __restrict__ Ct, const u16* __restrict__ E,
    int N, long sB, long sCn, long sCt, float sc, float alpha, float beta, int wn, int wt)
{
    __shared__ u16 As[64 * 40];
    __shared__ u16 Bs[64 * 40];
    const int tid = threadIdx.x;
    const int wave = tid >> 6, lane = tid & 63;
    const int wm = (wave >> 1) * 32, wnn = (wave & 1) * 32;
    const int i0 = blockIdx.x * 64, j0 = blockIdx.y * 64, bh = blockIdx.z;
    const u16* Ab = A + (size_t)bh * 65536;
    const u16* Bb = BT + (size_t)bh * sB;
    const int lr = tid >> 2, lk = (tid & 3) * 8;
    const int lm = lane & 15, lq = lane >> 4;
    fx4 acc[2][2];
#pragma unroll
    for (int a = 0; a < 2; ++a)
#pragma unroll
        for (int b = 0; b < 2; ++b) acc[a][b] = (fx4){0.f, 0.f, 0.f, 0.f};

    for (int k0 = 0; k0 < 256; k0 += 32) {
        uint4 a4 = *(const uint4*)(Ab + (size_t)(i0 + lr) * 256 + k0 + lk);
        uint4 b4 = *(const uint4*)(Bb + (size_t)(j0 + lr) * 256 + k0 + lk);
        __syncthreads();
        *(uint4*)(As + lr * 40 + lk) = a4;
        *(uint4*)(Bs + lr * 40 + lk) = b4;
        __syncthreads();
        bh8 lf[2], rf[2];
#pragma unroll
        for (int im = 0; im < 2; ++im)
            lf[im] = *(const bh8*)(As + (wm + im * 16 + lm) * 40 + lq * 8);
#pragma unroll
        for (int in = 0; in < 2; ++in)
            rf[in] = *(const bh8*)(Bs + (wnn + in * 16 + lm) * 40 + lq * 8);
#pragma unroll
        for (int im = 0; im < 2; ++im)
#pragma unroll
            for (int in = 0; in < 2; ++in)
                acc[im][in] = mfma16(lf[im], rf[in], acc[im][in]);
    }
#pragma unroll
    for (int im = 0; im < 2; ++im) {
#pragma unroll
        for (int in = 0; in < 2; ++in) {
            int n = j0 + wnn + in * 16 + lm;
            int m0 = i0 + wm + im * 16 + (lq << 2);
            float c[4];
#pragma unroll
            for (int r = 0; r < 4; ++r) {
                int m = m0 + r;
                float x = beta * acc[im][in][r];
                if (alpha != 0.f)
                    x += alpha * bf2f(E[(size_t)bh * 65536 + (size_t)m * 256 + n]);
                if (m == n) x += sc;
                c[r] = x;
            }
            if (wn) {
#pragma unroll
                for (int r = 0; r < 4; ++r)
                    Cn[(size_t)bh * sCn + (size_t)(m0 + r) * N + n] = f2bf(c[r]);
            }
            if (wt) {
                ushort4 o;
                o.x = f2bf(c[0]); o.y = f2bf(c[1]); o.z = f2bf(c[2]); o.w = f2bf(c[3]);
                *(ushort4*)(Ct + (size_t)bh * sCt + (size_t)n * 256 + m0) = o;
            }
        }
    }
}

// ---------------- attn3@v flash MFMA: per-wave online softmax over 512-n slice ----
// grid (8 mtile32, 4 nq, 32 bh), 256 thr. Writes unnormalized partial O (bf16)
// + (M, l) per (bh, part16, m).
__global__ __launch_bounds__(256) void attn3v_mfma_kernel(
    const u16* __restrict__ QLb, const u16* __restrict__ Kb,
    const u16* __restrict__ VTb, u16* __restrict__ PO, float* __restrict__ ML)
{
    __shared__ u16 Pl[4][32 * 72];   // per-wave P: [m 32][n 64 pad 72]
    const int tid = threadIdx.x;
    const int wave = tid >> 6, lane = tid & 63;
    const int q = lane >> 4, l15 = lane & 15;
    const int m0 = blockIdx.x * 32;
    const int part = blockIdx.y * 4 + wave;
    const int bh = blockIdx.z;
    const int nbase = part * 512;
    u16* Pw = Pl[wave];
    bh8 qf[2][2];
#pragma unroll
    for (int mt = 0; mt < 2; ++mt)
#pragma unroll
        for (int ks = 0; ks < 2; ++ks)
            qf[mt][ks] = *(const bh8*)(QLb + ((size_t)bh * NLAND + m0 + mt * 16 + l15) * DHEAD + ks * 32 + q * 8);
    float M[2] = {-1e30f, -1e30f};
    float L[2] = {0.f, 0.f};
    fx4 O[2][4];
#pragma unroll
    for (int mt = 0; mt < 2; ++mt)
#pragma unroll
        for (int dt = 0; dt < 4; ++dt) O[mt][dt] = (fx4){0.f, 0.f, 0.f, 0.f};

    for (int c = 0; c < 8; ++c) {
        const int n0 = nbase + c * 64;
        fx4 S[4][2];
#pragma unroll
        for (int nt = 0; nt < 4; ++nt)
#pragma unroll
            for (int mt = 0; mt < 2; ++mt) S[nt][mt] = (fx4){0.f, 0.f, 0.f, 0.f};
#pragma unroll
        for (int ks = 0; ks < 2; ++ks)
#pragma unroll
            for (int nt = 0; nt < 4; ++nt) {
                bh8 kf = *(const bh8*)(Kb + ((size_t)bh * N_SEQ + n0 + nt * 16 + l15) * DHEAD + ks * 32 + q * 8);
                S[nt][0] = mfma16(kf, qf[0][ks], S[nt][0]);   // D[n][m]: m=lane&15 side
                S[nt][1] = mfma16(kf, qf[1][ks], S[nt][1]);
            }
        // online softmax over n (a-side: regs + nt in-lane, quads via shfl 16/32)
#pragma unroll
        for (int mt = 0; mt < 2; ++mt) {
            float cm = -1e30f;
#pragma unroll
            for (int nt = 0; nt < 4; ++nt)
#pragma unroll
                for (int r = 0; r < 4; ++r) cm = fmaxf(cm, S[nt][mt][r]);
            cm = fmaxf(cm, __shfl_xor(cm, 16));
            cm = fmaxf(cm, __shfl_xor(cm, 32));
            float Mn = fmaxf(M[mt], cm);
            float al = __expf(M[mt] - Mn);
            M[mt] = Mn;
            L[mt] *= al;
#pragma unroll
            for (int dt = 0; dt < 4; ++dt) {
                O[mt][dt][0] *= al; O[mt][dt][1] *= al;
                O[mt][dt][2] *= al; O[mt][dt][3] *= al;
            }
            float ps = 0.f;
#pragma unroll
            for (int nt = 0; nt < 4; ++nt)
#pragma unroll
                for (int r = 0; r < 4; ++r) {
                    float p = __expf(S[nt][mt][r] - Mn);
                    ps += p;
                    Pw[(mt * 16 + l15) * 72 + nt * 16 + q * 4 + r] = f2bf(p);
                }
            ps += __shfl_xor(ps, 16);
            ps += __shfl_xor(ps, 32);
            L[mt] += ps;
        }
        // PV: O[d][m] += VT_frag x P_frag  (same-wave LDS, in-order, no barrier)
#pragma unroll
        for (int ks = 0; ks < 2; ++ks) {
            bh8 pf[2];
#pragma unroll
            for (int mt = 0; mt < 2; ++mt)
                pf[mt] = *(const bh8*)(Pw + (mt * 16 + l15) * 72 + ks * 32 + q * 8);
#pragma unroll
            for (int dt = 0; dt < 4; ++dt) {
                bh8 vf = *(const bh8*)(VTb + ((size_t)bh * DHEAD + dt * 16 + l15) * N_SEQ + n0 + ks * 32 + q * 8);
                O[0][dt] = mfma16(vf, pf[0], O[0][dt]);
                O[1][dt] = mfma16(vf, pf[1], O[1][dt]);
            }
        }
    }
#pragma unroll
    for (int mt = 0; mt < 2; ++mt) {
        size_t mrow = (size_t)(bh * 16 + part) * NLAND + m0 + mt * 16 + l15;
#pragma unroll
        for (int dt = 0; dt < 4; ++dt) {
            ushort4 o;
            o.x = f2bf(O[mt][dt][0]); o.y = f2bf(O[mt][dt][1]);
            o.z = f2bf(O[mt][dt][2]); o.w = f2bf(O[mt][dt][3]);
            *(ushort4*)(PO + mrow * DHEAD + dt * 16 + q * 4) = o;
        }
        if (q == 0) { ML[mrow * 2] = M[mt]; ML[mrow * 2 + 1] = L[mt]; }
    }
}

// ---------------- combine 16 flash partials -> W3VT[bh][64][256] ------------------
__global__ __launch_bounds__(64) void combine_kernel(
    const u16* __restrict__ PO, const float* __restrict__ ML, u16* __restrict__ W3VT)
{
    int m = blockIdx.x, bh = blockIdx.y, d = threadIdx.x;
    float Mg = -1e30f;
#pragma unroll
    for (int p = 0; p < 16; ++p)
        Mg = fmaxf(Mg, ML[((size_t)(bh * 16 + p) * NLAND + m) * 2]);
    float denom = 0.f, o = 0.f;
#pragma unroll
    for (int p = 0; p < 16; ++p) {
        size_t ix = (size_t)(bh * 16 + p) * NLAND + m;
        float w = __expf(ML[ix * 2] - Mg);
        denom += ML[ix * 2 + 1] * w;
        o += bf2f(PO[ix * DHEAD + d]) * w;
    }
    W3VT[((size_t)bh * DHEAD + d) * NLAND + m] = f2bf(o / denom);
}

// ---------------- outheads: attn1 softmax + @WM + conv residual, MFMA -------------
// grid (256 nblk32, 32 bh), 256 thr.
__global__ __launch_bounds__(256) void outheads_mfma_kernel(
    const u16* __restrict__ Qb, const u16* __restrict__ KLb,
    const u16* __restrict__ WMT, const u16* __restrict__ VTb,
    const u16* __restrict__ CW, u16* __restrict__ Y)
{
    __shared__ u16 Pl[32 * 264];     // [n 32][m 256 pad 264]
    __shared__ u16 vsh[64 * 72];     // [n 64 window][d 64 pad 72]
    __shared__ float wmax[4][32], wsum[4][32];
    __shared__ float cws[33];
    const int tid = threadIdx.x;
    const int wave = tid >> 6, lane = tid & 63;
    const int q = lane >> 4, l15 = lane & 15;
    const int bh = blockIdx.y;
    const int bb = bh >> 3, h = bh & 7;
    const int n0 = blockIdx.x * 32;
    // stage V window from VT: rows n0-16..n0+47, cols d 0..63
#pragma unroll
    for (int e = 0; e < 16; ++e) {
        int d = wave * 16 + e;
        int gn = n0 - 16 + lane;
        u16 v = (gn >= 0 && gn < N_SEQ) ? VTb[((size_t)bh * DHEAD + d) * N_SEQ + gn] : (u16)0;
        vsh[lane * 72 + d] = v;
    }
    if (tid < 33) cws[tid] = bf2f(CW[h * 33 + tid]);
    // S phase: wave handles m-range wave*64 (4 mtiles), direct global fragments
    fx4 S[2][4];
#pragma unroll
    for (int nt = 0; nt < 2; ++nt)
#pragma unroll
        for (int mt = 0; mt < 4; ++mt) S[nt][mt] = (fx4){0.f, 0.f, 0.f, 0.f};
#pragma unroll
    for (int ks = 0; ks < 2; ++ks) {
        bh8 qfr[2];
#pragma unroll
        for (int nt = 0; nt < 2; ++nt)
            qfr[nt] = *(const bh8*)(Qb + ((size_t)bh * N_SEQ + n0 + nt * 16 + l15) * DHEAD + ks * 32 + q * 8);
#pragma unroll
        for (int mt = 0; mt < 4; ++mt) {
            bh8 kf = *(const bh8*)(KLb + ((size_t)bh * NLAND + wave * 64 + mt * 16 + l15) * DHEAD + ks * 32 + q * 8);
            S[0][mt] = mfma16(qfr[0], kf, S[0][mt]);   // D[n][m]: n=ar, m=br
            S[1][mt] = mfma16(qfr[1], kf, S[1][mt]);
        }
    }
    // wave-partial max per n
#pragma unroll
    for (int nt = 0; nt < 2; ++nt)
#pragma unroll
        for (int r = 0; r < 4; ++r) {
            float pm = -1e30f;
#pragma unroll
            for (int mt = 0; mt < 4; ++mt) pm = fmaxf(pm, S[nt][mt][r]);
            pm = fmaxf(pm, __shfl_xor(pm, 1));
            pm = fmaxf(pm, __shfl_xor(pm, 2));
            pm = fmaxf(pm, __shfl_xor(pm, 4));
            pm = fmaxf(pm, __shfl_xor(pm, 8));
            if (l15 == 0) wmax[wave][nt * 16 + q * 4 + r] = pm;
        }
    __syncthreads();
    // exp + P write + wave-partial sums
#pragma unroll
    for (int nt = 0; nt < 2; ++nt)
#pragma unroll
        for (int r = 0; r < 4; ++r) {
            int nl = nt * 16 + q * 4 + r;
            float Mfull = fmaxf(fmaxf(wmax[0][nl], wmax[1][nl]), fmaxf(wmax[2][nl], wmax[3][nl]));
            float ps = 0.f;
#pragma unroll
            for (int mt = 0; mt < 4; ++mt) {
                float p = __expf(S[nt][mt][r] - Mfull);
                ps += p;
                Pl[nl * 264 + wave * 64 + mt * 16 + l15] = f2bf(p);
            }
            ps += __shfl_xor(ps, 1);
            ps += __shfl_xor(ps, 2);
            ps += __shfl_xor(ps, 4);
            ps += __shfl_xor(ps, 8);
            if (l15 == 0) wsum[wave][nl] = ps;
        }
    __syncthreads();
    // PV: O[d][n] = WMT_frag x P_frag; wave = d-tile
    fx4 O[2];
    O[0] = (fx4){0.f, 0.f, 0.f, 0.f};
    O[1] = (fx4){0.f, 0.f, 0.f, 0.f};
#pragma unroll
    for (int ks = 0; ks < 8; ++ks) {
        bh8 af = *(const bh8*)(WMT + ((size_t)bh * DHEAD + wave * 16 + l15) * NLAND + ks * 32 + q * 8);
#pragma unroll
        for (int nt = 0; nt < 2; ++nt) {
            bh8 pf = *(const bh8*)(Pl + (nt * 16 + l15) * 264 + ks * 32 + q * 8);
            O[nt] = mfma16(af, pf, O[nt]);
        }
    }
    // epilogue: normalize attn, add conv residual, store
#pragma unroll
    for (int nt = 0; nt < 2; ++nt) {
        int nl = nt * 16 + l15;
        float inv = 1.f / (wsum[0][nl] + wsum[1][nl] + wsum[2][nl] + wsum[3][nl]);
        fx4 v = O[nt];
        v[0] *= inv; v[1] *= inv; v[2] *= inv; v[3] *= inv;
#pragma unroll
        for (int t = 0; t < 33; ++t) {
            float w = cws[t];
            const u16* vp = vsh + (nl + t) * 72 + wave * 16 + q * 4;
            v[0] += w * bf2f(vp[0]); v[1] += w * bf2f(vp[1]);
            v[2] += w * bf2f(vp[2]); v[3] += w * bf2f(vp[3]);
        }
        ushort4 o;
        o.x = f2bf(v[0]); o.y = f2bf(v[1]); o.z = f2bf(v[2]); o.w = f2bf(v[3]);
        *(ushort4*)(Y + ((size_t)bb * N_SEQ + n0 + nl) * DMODEL + h * DHEAD + wave * 16 + q * 4) = o;
    }
}

// ---------------- final MFMA GEMM: out = x + y@w_out + b_out ----------------------
__global__ __launch_bounds__(256) void final_mfma_kernel(
    const u16* __restrict__ Y, const u16* __restrict__ WT,
    const u16* __restrict__ Bias, const u16* __restrict__ X, void* __restrict__ Out,
    const unsigned* __restrict__ flag)
{
    __shared__ u16 Xs[128 * 40];
    __shared__ u16 Ws[128 * 40];
    const int tid = threadIdx.x;
    const int wave = tid >> 6, lane = tid & 63;
    const int wrow = (wave >> 1) * 64, wcol = (wave & 1) * 64;
    const int i0 = blockIdx.x * 128;
    const int j0 = blockIdx.y * 128;
    const int lr = tid >> 2, lk = (tid & 3) * 8;
    const int lm = lane & 15, lq = lane >> 4;
    const unsigned isf32 = flag[0];
    fx4 acc[4][4];
#pragma unroll
    for (int a = 0; a < 4; ++a)
#pragma unroll
        for (int b = 0; b < 4; ++b) acc[a][b] = (fx4){0.f, 0.f, 0.f, 0.f};

    for (int k0 = 0; k0 < DMODEL; k0 += 32) {
        uint4 x0 = *(const uint4*)(Y + (size_t)(i0 + lr) * DMODEL + k0 + lk);
        uint4 x1 = *(const uint4*)(Y + (size_t)(i0 + 64 + lr) * DMODEL + k0 + lk);
        uint4 w0 = *(const uint4*)(WT + (size_t)(j0 + lr) * DMODEL + k0 + lk);
        uint4 w1 = *(const uint4*)(WT + (size_t)(j0 + 64 + lr) * DMODEL + k0 + lk);
        __syncthreads();
        *(uint4*)(Xs + lr * 40 + lk) = x0;
        *(uint4*)(Xs + (64 + lr) * 40 + lk) = x1;
        *(uint4*)(Ws + lr * 40 + lk) = w0;
        *(uint4*)(Ws + (64 + lr) * 40 + lk) = w1;
        __syncthreads();
        bh8 xf[4], wf[4];
#pragma unroll
        for (int im = 0; im < 4; ++im)
            xf[im] = *(const bh8*)(Xs + (wrow + im * 16 + lm) * 40 + lq * 8);
#pragma unroll
        for (int in = 0; in < 4; ++in)
            wf[in] = *(const bh8*)(Ws + (wcol + in * 16 + lm) * 40 + lq * 8);
#pragma unroll
        for (int im = 0; im < 4; ++im)
#pragma unroll
            for (int in = 0; in < 4; ++in)
                acc[im][in] = mfma16(wf[in], xf[im], acc[im][in]);
    }
#pragma unroll
    for (int im = 0; im < 4; ++im) {
        int m = i0 + wrow + im * 16 + lm;
#pragma unroll
        for (int in = 0; in < 4; ++in) {
            int nn = j0 + wcol + in * 16 + (lq << 2);
            ushort4 b4 = *(const ushort4*)(Bias + nn);
            ushort4 x4 = *(const ushort4*)(X + (size_t)m * DMODEL + nn);
            float c0 = acc[im][in][0] + bf2f(b4.x) + bf2f(x4.x);
            float c1 = acc[im][in][1] + bf2f(b4.y) + bf2f(x4.y);
            float c2 = acc[im][in][2] + bf2f(b4.z) + bf2f(x4.z);
            float c3 = acc[im][in][3] + bf2f(b4.w) + bf2f(x4.w);
            if (isf32) {
                *(float4*)((float*)Out + (size_t)m * DMODEL + nn) = make_float4(c0, c1, c2, c3);
            } else {
                ushort4 o;
                o.x = f2bf(c0); o.y = f2bf(c1); o.z = f2bf(c2); o.w = f2bf(c3);
                *(ushort4*)((u16*)Out + (size_t)m * DMODEL + nn) = o;
            }
        }
    }
}

extern "C" void kernel_launch(void* const* d_in, const int* in_sizes, int n_in,
                              void* d_out, int out_size, void* d_ws, size_t ws_size,
                              hipStream_t stream)
{
    (void)in_sizes; (void)n_in; (void)out_size; (void)ws_size;
    char* ws = (char*)d_ws;
    u16*   Xc    = (u16*)(ws + 0);            // 33,554,432
    u16*   WqkvT = (u16*)(ws + 33554432);     //  1,572,864
    u16*   WoutT = (u16*)(ws + 35127296);     //    524,288
    u16*   Boutc = (u16*)(ws + 35651584);     //      1,024
    u16*   CWc   = (u16*)(ws + 35652608);     //      1,024
    u16*   Qb    = (u16*)(ws + 35653632);     // 33,554,432  [bh][n][d]
    u16*   Kb    = (u16*)(ws + 69208064);     // 33,554,432  [bh][n][d]
    u16*   VTb   = (u16*)(ws + 102762496);    // 33,554,432  [bh][d][n]
    float* QL    = (float*)(ws + 136316928);  //  2,097,152
    float* KL    = (float*)(ws + 138414080);  //  2,097,152
    u16*   QLb   = (u16*)(ws + 140511232);    //  1,048,576
    u16*   KLb   = (u16*)(ws + 141559808);    //  1,048,576
    u16*   W3VT  = (u16*)(ws + 142608384);    //  1,048,576  [bh][64][256]
    u16*   WMT   = (u16*)(ws + 143656960);    //  1,048,576  [bh][64][256]
    u16*   A2b   = (u16*)(ws + 144705536);    //  4,194,304
    u16*   zA    = (u16*)(ws + 148899840);    //  4,194,304
    u16*   zAT   = (u16*)(ws + 153094144);    //  4,194,304
    // overlay region 157,288,448..190,842,880 (33,554,432 B):
    //   phase 1 (attn2..f2b):  A2 fp32 (8,388,608)
    //   phase 2 (attn3v):      PO bf16 (16,777,216) + ML (1,048,576)
    //   phase 3 (pinv):        A2-slot dead; zB..t3T live
    //   phase 4 (outheads on): Yb (33,554,432)
    float* A2    = (float*)(ws + 157288448);
    u16*   PO    = (u16*)(ws + 157288448);
    float* ML    = (float*)(ws + 174065664);
    u16*   zB    = (u16*)(ws + 165677056);
    u16*   zBT   = (u16*)(ws + 169871360);
    u16*   xz    = (u16*)(ws + 174065664);
    u16*   xzT   = (u16*)(ws + 178259968);
    u16*   t2T   = (u16*)(ws + 182454272);
    u16*   t3T   = (u16*)(ws + 186648576);
    u16*   Yb    = (u16*)(ws + 157288448);
    unsigned* SCAL = (unsigned*)(ws + 190842880);

    detect_kernel<<<1, 256, 0, stream>>>((const u16*)d_in[0], SCAL + 2);
    convert_kernel<<<65536, 256, 0, stream>>>(d_in[0], Xc, 16777216, SCAL + 2);
    wtrans_kernel<<<3072, 256, 0, stream>>>(d_in[1], WqkvT, 512, 1536, SCAL + 2);
    wtrans_kernel<<<1024, 256, 0, stream>>>(d_in[2], WoutT, 512, 512, SCAL + 2);
    convert_kernel<<<2, 256, 0, stream>>>(d_in[3], Boutc, 512, SCAL + 2);
    convert_kernel<<<2, 256, 0, stream>>>(d_in[4], CWc, 264, SCAL + 2);

    qkv_mfma_kernel<<<dim3(256, 12), 256, 0, stream>>>(Xc, WqkvT, Qb, Kb, VTb);
    pool_kernel<<<dim3(256, BH), 64, 0, stream>>>(Qb, Kb, QL, KL, QLb, KLb);
    attn2_kernel<<<dim3(256, BH), 256, 0, stream>>>(QL, KL, A2);
    init_scal_kernel<<<1, 64, 0, stream>>>(SCAL);
    absmax_kernel<<<32, 256, 0, stream>>>(A2, SCAL);
    z0_kernel<<<8192, 256, 0, stream>>>(A2, SCAL, zA, zAT);
    f2b_kernel<<<8192, 256, 0, stream>>>(A2, A2b, 2097152);

    // flash attn3@v (overwrites A2 region -> PO/ML), then combine -> W3VT
    attn3v_mfma_kernel<<<dim3(8, 4, BH), 256, 0, stream>>>(QLb, Kb, VTb, PO, ML);
    combine_kernel<<<dim3(256, BH), 64, 0, stream>>>(PO, ML, W3VT);

    u16 *z = zA, *zT = zAT, *zn = zB, *znT = zBT;
    for (int it = 0; it < 6; ++it) {
        bgemm_mfma_kernel<<<dim3(4, 4, 32), 256, 0, stream>>>(
            A2b, zT, xz, xzT, A2b, 256, 65536, 65536, 65536, 0.f, 0.f, 1.f, 1, 1);
        bgemm_mfma_kernel<<<dim3(4, 4, 32), 256, 0, stream>>>(
            xz, xzT, xz, t2T, xz, 256, 65536, 65536, 65536, 15.f, -7.f, 1.f, 0, 1);
        bgemm_mfma_kernel<<<dim3(4, 4, 32), 256, 0, stream>>>(
            xz, t2T, xz, t3T, xz, 256, 65536, 65536, 65536, 13.f, 0.f, -1.f, 0, 1);
        bgemm_mfma_kernel<<<dim3(4, 4, 32), 256, 0, stream>>>(
            z, t3T, zn, znT, xz, 256, 65536, 65536, 65536, 0.f, 0.f, 0.25f, 1, 1);
        u16* t;
        t = z; z = zn; zn = t;
        t = zT; zT = znT; znT = t;
    }
    // WM^T = (z @ w3v)^T -> [bh][64][256]
    bgemm_mfma_kernel<<<dim3(4, 1, 32), 256, 0, stream>>>(
        z, W3VT, WMT, WMT, xz, 64, 16384, 16384, 16384, 0.f, 0.f, 1.f, 0, 1);
    // y = softmax(q k_l^T) @ WM + conv_res(v)
    outheads_mfma_kernel<<<dim3(256, BH), 256, 0, stream>>>(Qb, KLb, WMT, VTb, CWc, Yb);
    // out = x + y @ w_out + b_out
    final_mfma_kernel<<<dim3(256, 4), 256, 0, stream>>>(Yb, WoutT, Boutc, Xc, d_out, SCAL + 2);
}

// Round 5
// 809.142 us; speedup vs baseline: 4.9049x; 1.0474x over previous
//
#include <hip/hip_runtime.h>

// Nystrom attention, MI355X round 5: async global_load_lds + swizzle for dense
// GEMMs, de-fused depthwise conv, 64-n outheads blocks.
// b=4, n=8192, dim=512, h=8, dh=64, m=256 landmarks, pinv iters=6, conv k=33.

#define N_SEQ 8192
#define DMODEL 512
#define NHEAD 8
#define DHEAD 64
#define NLAND 256
#define BH 32

typedef unsigned short u16;
typedef __attribute__((ext_vector_type(8))) short bh8;
typedef __attribute__((ext_vector_type(4))) float fx4;

__device__ __forceinline__ float bf2f(u16 u) { return __uint_as_float(((unsigned)u) << 16); }
__device__ __forceinline__ u16 f2bf(float f) {
    unsigned x = __float_as_uint(f);
    return (u16)((x + 0x7fffu + ((x >> 16) & 1u)) >> 16);
}
__device__ __forceinline__ fx4 mfma16(bh8 a, bh8 b, fx4 c) {
    return __builtin_amdgcn_mfma_f32_16x16x32_bf16(a, b, c, 0, 0, 0);
}
// async 16B global->LDS; lds base must be wave-uniform, HW scatters lane*16B
__device__ __forceinline__ void gload16(u16* lds, const u16* g) {
    __builtin_amdgcn_global_load_lds(
        (const __attribute__((address_space(1))) unsigned int*)g,
        (__attribute__((address_space(3))) unsigned int*)lds, 16, 0, 0);
}

// ---------------- dtype probe -----------------------------------------------------
__global__ void detect_kernel(const u16* __restrict__ X, unsigned* flag_out)
{
    __shared__ int cnt;
    if (threadIdx.x == 0) cnt = 0;
    __syncthreads();
    u16 u = X[threadIdx.x * 2];
    int e = (u >> 7) & 0xFF;
    int insane = (u != 0) && (e < 90 || e > 140);
    atomicAdd(&cnt, insane);
    __syncthreads();
    if (threadIdx.x == 0) flag_out[0] = (cnt > 64) ? 1u : 0u;
}

__global__ __launch_bounds__(256) void convert_kernel(
    const void* __restrict__ in, u16* __restrict__ out, int n, const unsigned* __restrict__ flag)
{
    int i = blockIdx.x * 256 + threadIdx.x;
    if (i >= n) return;
    if (flag[0]) out[i] = f2bf(((const float*)in)[i]);
    else         out[i] = ((const u16*)in)[i];
}

__global__ __launch_bounds__(256) void wtrans_kernel(
    const void* __restrict__ in, u16* __restrict__ out, int rows, int cols,
    const unsigned* __restrict__ flag)
{
    int idx = blockIdx.x * 256 + threadIdx.x;
    if (idx >= rows * cols) return;
    int r = idx / cols, c = idx % cols;
    float v = flag[0] ? ((const float*)in)[idx] : bf2f(((const u16*)in)[idx]);
    out[(size_t)c * rows + r] = f2bf(v);
}

__global__ __launch_bounds__(256) void f2b_kernel(const float* __restrict__ in, u16* __restrict__ out, int n)
{
    int i = blockIdx.x * 256 + threadIdx.x;
    if (i < n) out[i] = f2bf(in[i]);
}

// ---------------- QKV MFMA GEMM (async staging + xor swizzle) ---------------------
// LDS rows 64B unpadded; stored chunk-pos p holds global chunk p^(row&7).
__global__ __launch_bounds__(256) void qkv_mfma_kernel(
    const u16* __restrict__ X, const u16* __restrict__ WT,
    u16* __restrict__ Q, u16* __restrict__ K, u16* __restrict__ VT)
{
    __shared__ u16 Xs[128 * 64];
    __shared__ u16 Ws[128 * 64];
    const int tid = threadIdx.x;
    const int wave = tid >> 6, lane = tid & 63;
    const int wrow = (wave >> 1) * 64, wcol = (wave & 1) * 64;
    const int i0 = blockIdx.x * 128;
    const int j0 = blockIdx.y * 128;
    const int la = lane >> 3, lb = lane & 7;
    const int lm = lane & 15, lq = lane >> 4;
    const int sw = lm & 7;
    const int sc = (lb ^ la) * 8;
    fx4 acc[4][4];
#pragma unroll
    for (int a = 0; a < 4; ++a)
#pragma unroll
        for (int b = 0; b < 4; ++b) acc[a][b] = (fx4){0.f, 0.f, 0.f, 0.f};

    for (int k0 = 0; k0 < DMODEL; k0 += 64) {
        __syncthreads();
#pragma unroll
        for (int jj = 0; jj < 4; ++jj) {
            int rb = wave * 32 + jj * 8;
            gload16(Xs + rb * 64, X + (size_t)(i0 + rb + la) * DMODEL + k0 + sc);
            gload16(Ws + rb * 64, WT + (size_t)(j0 + rb + la) * DMODEL + k0 + sc);
        }
        __syncthreads();
#pragma unroll
        for (int ks = 0; ks < 2; ++ks) {
            const int po = ((ks * 4 + lq) ^ sw) * 8;
            bh8 xf[4], wf[4];
#pragma unroll
            for (int im = 0; im < 4; ++im)
                xf[im] = *(const bh8*)(Xs + (wrow + im * 16 + lm) * 64 + po);
#pragma unroll
            for (int in = 0; in < 4; ++in)
                wf[in] = *(const bh8*)(Ws + (wcol + in * 16 + lm) * 64 + po);
#pragma unroll
            for (int im = 0; im < 4; ++im)
#pragma unroll
                for (int in = 0; in < 4; ++in)
                    acc[im][in] = mfma16(wf[in], xf[im], acc[im][in]);
        }
    }
#pragma unroll
    for (int im = 0; im < 4; ++im) {
        int m = i0 + wrow + im * 16 + lm;
        int bb = m >> 13, ns = m & (N_SEQ - 1);
#pragma unroll
        for (int in = 0; in < 4; ++in) {
            int nn = j0 + wcol + in * 16 + (lq << 2);
            int which = nn >> 9;
            int h = (nn >> 6) & 7;
            int d = nn & 63;
            if (which == 2) {
                size_t vb = (size_t)(bb * NHEAD + h) * DHEAD;
#pragma unroll
                for (int cc = 0; cc < 4; ++cc)
                    VT[(vb + d + cc) * N_SEQ + ns] = f2bf(acc[im][in][cc]);
            } else {
                u16* dst = (which == 0) ? Q : K;
                float s = (which == 0) ? 0.125f : 1.f;
                ushort4 o;
                o.x = f2bf(acc[im][in][0] * s); o.y = f2bf(acc[im][in][1] * s);
                o.z = f2bf(acc[im][in][2] * s); o.w = f2bf(acc[im][in][3] * s);
                *(ushort4*)(dst + ((size_t)(bb * NHEAD + h) * N_SEQ + ns) * DHEAD + d) = o;
            }
        }
    }
}

// ---------------- landmark pooling ------------------------------------------------
__global__ __launch_bounds__(64) void pool_kernel(
    const u16* __restrict__ Q, const u16* __restrict__ K,
    float* __restrict__ QL, float* __restrict__ KL,
    u16* __restrict__ QLb, u16* __restrict__ KLb)
{
    int m = blockIdx.x, bh = blockIdx.y, d = threadIdx.x;
    size_t base = ((size_t)bh * N_SEQ + m * 32) * DHEAD + d;
    float sq = 0.f, sk = 0.f;
#pragma unroll
    for (int i = 0; i < 32; ++i) {
        sq += bf2f(Q[base + i * DHEAD]);
        sk += bf2f(K[base + i * DHEAD]);
    }
    size_t ob = ((size_t)bh * NLAND + m) * DHEAD + d;
    sq *= (1.f / 32.f); sk *= (1.f / 32.f);
    QL[ob] = sq; KL[ob] = sk;
    QLb[ob] = f2bf(sq); KLb[ob] = f2bf(sk);
}

// ---------------- attn2 = softmax(q_l @ k_l^T) ------------------------------------
__global__ __launch_bounds__(256) void attn2_kernel(
    const float* __restrict__ QL, const float* __restrict__ KL, float* __restrict__ A2)
{
    __shared__ float qrow[64];
    __shared__ float red[256];
    int i = blockIdx.x, bh = blockIdx.y, j = threadIdx.x;
    if (j < 64) qrow[j] = QL[((size_t)bh * NLAND + i) * DHEAD + j];
    __syncthreads();
    const float* kr = KL + ((size_t)bh * NLAND + j) * DHEAD;
    float lg = 0.f;
#pragma unroll
    for (int d = 0; d < 64; ++d) lg += qrow[d] * kr[d];
    red[j] = lg; __syncthreads();
    for (int s = 128; s > 0; s >>= 1) { if (j < s) red[j] = fmaxf(red[j], red[j + s]); __syncthreads(); }
    float mx = red[0]; __syncthreads();
    float p = __expf(lg - mx);
    red[j] = p; __syncthreads();
    for (int s = 128; s > 0; s >>= 1) { if (j < s) red[j] += red[j + s]; __syncthreads(); }
    float sum = red[0];
    A2[((size_t)bh * NLAND + i) * NLAND + j] = p / sum;
}

__global__ void init_scal_kernel(unsigned* scal) { if (threadIdx.x < 2) scal[threadIdx.x] = 0u; }

__global__ __launch_bounds__(256) void absmax_kernel(const float* __restrict__ A2, unsigned* scal)
{
    __shared__ float red[256];
    int bh = blockIdx.x, t = threadIdx.x;
    const float* Ab = A2 + (size_t)bh * 65536;
    float cs = 0.f, rs = 0.f;
    for (int j = 0; j < 256; ++j) cs += fabsf(Ab[t * 256 + j]);
    for (int i = 0; i < 256; ++i) rs += fabsf(Ab[i * 256 + t]);
    red[t] = cs; __syncthreads();
    for (int s = 128; s > 0; s >>= 1) { if (t < s) red[t] = fmaxf(red[t], red[t + s]); __syncthreads(); }
    if (t == 0) atomicMax(scal + 0, __float_as_uint(red[0]));
    __syncthreads();
    red[t] = rs; __syncthreads();
    for (int s = 128; s > 0; s >>= 1) { if (t < s) red[t] = fmaxf(red[t], red[t + s]); __syncthreads(); }
    if (t == 0) atomicMax(scal + 1, __float_as_uint(red[0]));
}

__global__ __launch_bounds__(256) void z0_kernel(
    const float* __restrict__ A2, const unsigned* __restrict__ scal,
    u16* __restrict__ zb, u16* __restrict__ zbT)
{
    float inv = 1.f / (__uint_as_float(scal[0]) * __uint_as_float(scal[1]));
    size_t idx = (size_t)blockIdx.x * 256 + threadIdx.x;
    size_t bh = idx >> 16;
    int r = (int)(idx & 65535);
    int i = r >> 8, j = r & 255;
    zb[idx]  = f2bf(A2[(bh << 16) + (size_t)j * 256 + i] * inv);
    zbT[idx] = f2bf(A2[idx] * inv);
}

// ---------------- batched MFMA GEMM for pinv --------------------------------------
__global__ __launch_bounds__(256) void bgemm_mfma_kernel(
    const u16* __restrict__ A, const u16* __restrict__ BT,
    u16* __restrict__ Cn, u16* __restrict__ Ct, const u16* __restrict__ E,
    int N, long sB, long sCn, long sCt, float sc, float alpha, float beta, int wn, int wt)
{
    __shared__ u16 As[64 * 40];
    __shared__ u16 Bs[64 * 40];
    const int tid = threadIdx.x;
    const int wave = tid >> 6, lane = tid & 63;
    const int wm = (wave >> 1) * 32, wnn = (wave & 1) * 32;
    const int i0 = blockIdx.x * 64, j0 = blockIdx.y * 64, bh = blockIdx.z;
    const u16* Ab = A + (size_t)bh * 65536;
    const u16* Bb = BT + (size_t)bh * sB;
    const int lr = tid >> 2, lk = (tid & 3) * 8;
    const int lm = lane & 15, lq = lane >> 4;
    fx4 acc[2][2];
#pragma unroll
    for (int a = 0; a < 2; ++a)
#pragma unroll
        for (int b = 0; b < 2; ++b) acc[a][b] = (fx4){0.f, 0.f, 0.f, 0.f};

    for (int k0 = 0; k0 < 256; k0 += 32) {
        uint4 a4 = *(const uint4*)(Ab + (size_t)(i0 + lr) * 256 + k0 + lk);
        uint4 b4 = *(const uint4*)(Bb + (size_t)(j0 + lr) * 256 + k0 + lk);
        __syncthreads();
        *(uint4*)(As + lr * 40 + lk) = a4;
        *(uint4*)(Bs + lr * 40 + lk) = b4;
        __syncthreads();
        bh8 lf[2], rf[2];
#pragma unroll
        for (int im = 0; im < 2; ++im)
            lf[im] = *(const bh8*)(As + (wm + im * 16 + lm) * 40 + lq * 8);
#pragma unroll
        for (int in = 0; in < 2; ++in)
            rf[in] = *(const bh8*)(Bs + (wnn + in * 16 + lm) * 40 + lq * 8);
#pragma unroll
        for (int im = 0; im < 2; ++im)
#pragma unroll
            for (int in = 0; in < 2; ++in)
                acc[im][in] = mfma16(lf[im], rf[in], acc[im][in]);
    }
#pragma unroll
    for (int im = 0; im < 2; ++im) {
#pragma unroll
        for (int in = 0; in < 2; ++in) {
            int n = j0 + wnn + in * 16 + lm;
            int m0 = i0 + wm + im * 16 + (lq << 2);
            float c[4];
#pragma unroll
            for (int r = 0; r < 4; ++r) {
                int m = m0 + r;
                float x = beta * acc[im][in][r];
                if (alpha != 0.f)
                    x += alpha * bf2f(E[(size_t)bh * 65536 + (size_t)m * 256 + n]);
                if (m == n) x += sc;
                c[r] = x;
            }
            if (wn) {
#pragma unroll
                for (int r = 0; r < 4; ++r)
                    Cn[(size_t)bh * sCn + (size_t)(m0 + r) * N + n] = f2bf(c[r]);
            }
            if (wt) {
                ushort4 o;
                o.x = f2bf(c[0]); o.y = f2bf(c[1]); o.z = f2bf(c[2]); o.w = f2bf(c[3]);
                *(ushort4*)(Ct + (size_t)bh * sCt + (size_t)n * 256 + m0) = o;
            }
        }
    }
}

// ---------------- attn3@v flash MFMA ----------------------------------------------
__global__ __launch_bounds__(256) void attn3v_mfma_kernel(
    const u16* __restrict__ QLb, const u16* __restrict__ Kb,
    const u16* __restrict__ VTb, u16* __restrict__ PO, float* __restrict__ ML)
{
    __shared__ u16 Pl[4][32 * 72];
    const int tid = threadIdx.x;
    const int wave = tid >> 6, lane = tid & 63;
    const int q = lane >> 4, l15 = lane & 15;
    const int m0 = blockIdx.x * 32;
    const int part = blockIdx.y * 4 + wave;
    const int bh = blockIdx.z;
    const int nbase = part * 512;
    u16* Pw = Pl[wave];
    bh8 qf[2][2];
#pragma unroll
    for (int mt = 0; mt < 2; ++mt)
#pragma unroll
        for (int ks = 0; ks < 2; ++ks)
            qf[mt][ks] = *(const bh8*)(QLb + ((size_t)bh * NLAND + m0 + mt * 16 + l15) * DHEAD + ks * 32 + q * 8);
    float M[2] = {-1e30f, -1e30f};
    float L[2] = {0.f, 0.f};
    fx4 O[2][4];
#pragma unroll
    for (int mt = 0; mt < 2; ++mt)
#pragma unroll
        for (int dt = 0; dt < 4; ++dt) O[mt][dt] = (fx4){0.f, 0.f, 0.f, 0.f};

    for (int c = 0; c < 8; ++c) {
        const int n0 = nbase + c * 64;
        fx4 S[4][2];
#pragma unroll
        for (int nt = 0; nt < 4; ++nt)
#pragma unroll
            for (int mt = 0; mt < 2; ++mt) S[nt][mt] = (fx4){0.f, 0.f, 0.f, 0.f};
#pragma unroll
        for (int ks = 0; ks < 2; ++ks)
#pragma unroll
            for (int nt = 0; nt < 4; ++nt) {
                bh8 kf = *(const bh8*)(Kb + ((size_t)bh * N_SEQ + n0 + nt * 16 + l15) * DHEAD + ks * 32 + q * 8);
                S[nt][0] = mfma16(kf, qf[0][ks], S[nt][0]);
                S[nt][1] = mfma16(kf, qf[1][ks], S[nt][1]);
            }
#pragma unroll
        for (int mt = 0; mt < 2; ++mt) {
            float cm = -1e30f;
#pragma unroll
            for (int nt = 0; nt < 4; ++nt)
#pragma unroll
                for (int r = 0; r < 4; ++r) cm = fmaxf(cm, S[nt][mt][r]);
            cm = fmaxf(cm, __shfl_xor(cm, 16));
            cm = fmaxf(cm, __shfl_xor(cm, 32));
            float Mn = fmaxf(M[mt], cm);
            float al = __expf(M[mt] - Mn);
            M[mt] = Mn;
            L[mt] *= al;
#pragma unroll
            for (int dt = 0; dt < 4; ++dt) {
                O[mt][dt][0] *= al; O[mt][dt][1] *= al;
                O[mt][dt][2] *= al; O[mt][dt][3] *= al;
            }
            float ps = 0.f;
#pragma unroll
            for (int nt = 0; nt < 4; ++nt)
#pragma unroll
                for (int r = 0; r < 4; ++r) {
                    float p = __expf(S[nt][mt][r] - Mn);
                    ps += p;
                    Pw[(mt * 16 + l15) * 72 + nt * 16 + q * 4 + r] = f2bf(p);
                }
            ps += __shfl_xor(ps, 16);
            ps += __shfl_xor(ps, 32);
            L[mt] += ps;
        }
#pragma unroll
        for (int ks = 0; ks < 2; ++ks) {
            bh8 pf[2];
#pragma unroll
            for (int mt = 0; mt < 2; ++mt)
                pf[mt] = *(const bh8*)(Pw + (mt * 16 + l15) * 72 + ks * 32 + q * 8);
#pragma unroll
            for (int dt = 0; dt < 4; ++dt) {
                bh8 vf = *(const bh8*)(VTb + ((size_t)bh * DHEAD + dt * 16 + l15) * N_SEQ + n0 + ks * 32 + q * 8);
                O[0][dt] = mfma16(vf, pf[0], O[0][dt]);
                O[1][dt] = mfma16(vf, pf[1], O[1][dt]);
            }
        }
    }
#pragma unroll
    for (int mt = 0; mt < 2; ++mt) {
        size_t mrow = (size_t)(bh * 16 + part) * NLAND + m0 + mt * 16 + l15;
#pragma unroll
        for (int dt = 0; dt < 4; ++dt) {
            ushort4 o;
            o.x = f2bf(O[mt][dt][0]); o.y = f2bf(O[mt][dt][1]);
            o.z = f2bf(O[mt][dt][2]); o.w = f2bf(O[mt][dt][3]);
            *(ushort4*)(PO + mrow * DHEAD + dt * 16 + q * 4) = o;
        }
        if (q == 0) { ML[mrow * 2] = M[mt]; ML[mrow * 2 + 1] = L[mt]; }
    }
}

__global__ __launch_bounds__(64) void combine_kernel(
    const u16* __restrict__ PO, const float* __restrict__ ML, u16* __restrict__ W3VT)
{
    int m = blockIdx.x, bh = blockIdx.y, d = threadIdx.x;
    float Mg = -1e30f;
#pragma unroll
    for (int p = 0; p < 16; ++p)
        Mg = fmaxf(Mg, ML[((size_t)(bh * 16 + p) * NLAND + m) * 2]);
    float denom = 0.f, o = 0.f;
#pragma unroll
    for (int p = 0; p < 16; ++p) {
        size_t ix = (size_t)(bh * 16 + p) * NLAND + m;
        float w = __expf(ML[ix * 2] - Mg);
        denom += ML[ix * 2 + 1] * w;
        o += bf2f(PO[ix * DHEAD + d]) * w;
    }
    W3VT[((size_t)bh * DHEAD + d) * NLAND + m] = f2bf(o / denom);
}

// ---------------- depthwise conv residual: RT[bh*64+d][n] from VT -----------------
__global__ __launch_bounds__(256) void conv_kernel(
    const u16* __restrict__ VT, const u16* __restrict__ CW, u16* __restrict__ RT)
{
    __shared__ float vl[2080];
    __shared__ float cws[33];
    const int tid = threadIdx.x;
    const int c0 = blockIdx.x * 2048;
    const int row = blockIdx.y;               // bh*64 + d
    const int h = (row >> 6) & 7;
    const u16* src = VT + (size_t)row * N_SEQ;
    for (int i = tid; i < 2080; i += 256) {
        int gn = c0 - 16 + i;
        vl[i] = (gn >= 0 && gn < N_SEQ) ? bf2f(src[gn]) : 0.f;
    }
    if (tid < 33) cws[tid] = bf2f(CW[h * 33 + tid]);
    __syncthreads();
    float v[40];
    const int base = tid * 8;
#pragma unroll
    for (int i = 0; i < 40; ++i) v[i] = vl[base + i];
    float s[8];
#pragma unroll
    for (int j = 0; j < 8; ++j) {
        float a = 0.f;
#pragma unroll
        for (int t = 0; t < 33; ++t) a += cws[t] * v[j + t];
        s[j] = a;
    }
    u16* dst = RT + (size_t)row * N_SEQ + c0 + base;
    ushort4 o0, o1;
    o0.x = f2bf(s[0]); o0.y = f2bf(s[1]); o0.z = f2bf(s[2]); o0.w = f2bf(s[3]);
    o1.x = f2bf(s[4]); o1.y = f2bf(s[5]); o1.z = f2bf(s[6]); o1.w = f2bf(s[7]);
    *(ushort4*)dst = o0;
    *(ushort4*)(dst + 4) = o1;
}

// ---------------- outheads: attn1 softmax + @WM + RT residual, 64 n/block ---------
__global__ __launch_bounds__(256) void outheads_mfma_kernel(
    const u16* __restrict__ Qb, const u16* __restrict__ KLb,
    const u16* __restrict__ WMT, const u16* __restrict__ RT,
    u16* __restrict__ Y)
{
    __shared__ u16 Pl[64 * 264];
    __shared__ float wmax[4][64];
    __shared__ float wsum[4][64];
    const int tid = threadIdx.x;
    const int wave = tid >> 6, lane = tid & 63;
    const int q = lane >> 4, l15 = lane & 15;
    const int bh = blockIdx.y;
    const int bb = bh >> 3, h = bh & 7;
    const int n0 = blockIdx.x * 64;
    fx4 S[4][4];
#pragma unroll
    for (int a = 0; a < 4; ++a)
#pragma unroll
        for (int b = 0; b < 4; ++b) S[a][b] = (fx4){0.f, 0.f, 0.f, 0.f};
#pragma unroll
    for (int ks = 0; ks < 2; ++ks) {
        bh8 qfr[4];
#pragma unroll
        for (int nt = 0; nt < 4; ++nt)
            qfr[nt] = *(const bh8*)(Qb + ((size_t)bh * N_SEQ + n0 + nt * 16 + l15) * DHEAD + ks * 32 + q * 8);
#pragma unroll
        for (int mt = 0; mt < 4; ++mt) {
            bh8 kf = *(const bh8*)(KLb + ((size_t)bh * NLAND + wave * 64 + mt * 16 + l15) * DHEAD + ks * 32 + q * 8);
#pragma unroll
            for (int nt = 0; nt < 4; ++nt)
                S[nt][mt] = mfma16(qfr[nt], kf, S[nt][mt]);   // D[n][m]
        }
    }
#pragma unroll
    for (int nt = 0; nt < 4; ++nt)
#pragma unroll
        for (int r = 0; r < 4; ++r) {
            float pm = fmaxf(fmaxf(S[nt][0][r], S[nt][1][r]), fmaxf(S[nt][2][r], S[nt][3][r]));
            pm = fmaxf(pm, __shfl_xor(pm, 1));
            pm = fmaxf(pm, __shfl_xor(pm, 2));
            pm = fmaxf(pm, __shfl_xor(pm, 4));
            pm = fmaxf(pm, __shfl_xor(pm, 8));
            if (l15 == 0) wmax[wave][nt * 16 + q * 4 + r] = pm;
        }
    __syncthreads();
#pragma unroll
    for (int nt = 0; nt < 4; ++nt)
#pragma unroll
        for (int r = 0; r < 4; ++r) {
            int nl = nt * 16 + q * 4 + r;
            float Mf = fmaxf(fmaxf(wmax[0][nl], wmax[1][nl]), fmaxf(wmax[2][nl], wmax[3][nl]));
            float ps = 0.f;
#pragma unroll
            for (int mt = 0; mt < 4; ++mt) {
                float p = __expf(S[nt][mt][r] - Mf);
                ps += p;
                Pl[nl * 264 + wave * 64 + mt * 16 + l15] = f2bf(p);
            }
            ps += __shfl_xor(ps, 1);
            ps += __shfl_xor(ps, 2);
            ps += __shfl_xor(ps, 4);
            ps += __shfl_xor(ps, 8);
            if (l15 == 0) wsum[wave][nl] = ps;
        }
    __syncthreads();
    fx4 O[4];
#pragma unroll
    for (int nt = 0; nt < 4; ++nt) O[nt] = (fx4){0.f, 0.f, 0.f, 0.f};
#pragma unroll
    for (int ks = 0; ks < 8; ++ks) {
        bh8 af = *(const bh8*)(WMT + ((size_t)bh * DHEAD + wave * 16 + l15) * NLAND + ks * 32 + q * 8);
#pragma unroll
        for (int nt = 0; nt < 4; ++nt) {
            bh8 pf = *(const bh8*)(Pl + (size_t)(nt * 16 + l15) * 264 + ks * 32 + q * 8);
            O[nt] = mfma16(af, pf, O[nt]);   // D[d][n]
        }
    }
#pragma unroll
    for (int nt = 0; nt < 4; ++nt) {
        int nl = nt * 16 + l15;
        float inv = 1.f / (wsum[0][nl] + wsum[1][nl] + wsum[2][nl] + wsum[3][nl]);
        int d0 = wave * 16 + (q << 2);
        fx4 v = O[nt];
#pragma unroll
        for (int c = 0; c < 4; ++c)
            v[c] = v[c] * inv + bf2f(RT[(size_t)(bh * DHEAD + d0 + c) * N_SEQ + n0 + nl]);
        ushort4 o;
        o.x = f2bf(v[0]); o.y = f2bf(v[1]); o.z = f2bf(v[2]); o.w = f2bf(v[3]);
        *(ushort4*)(Y + ((size_t)bb * N_SEQ + n0 + nl) * DMODEL + h * DHEAD + d0) = o;
    }
}

// ---------------- final MFMA GEMM (async staging + swizzle) -----------------------
__global__ __launch_bounds__(256) void final_mfma_kernel(
    const u16* __restrict__ Y, const u16* __restrict__ WT,
    const u16* __restrict__ Bias, const u16* __restrict__ X, void* __restrict__ Out,
    const unsigned* __restrict__ flag)
{
    __shared__ u16 Xs[128 * 64];
    __shared__ u16 Ws[128 * 64];
    const int tid = threadIdx.x;
    const int wave = tid >> 6, lane = tid & 63;
    const int wrow = (wave >> 1) * 64, wcol = (wave & 1) * 64;
    const int i0 = blockIdx.x * 128;
    const int j0 = blockIdx.y * 128;
    const int la = lane >> 3, lb = lane & 7;
    const int lm = lane & 15, lq = lane >> 4;
    const int sw = lm & 7;
    const int sc = (lb ^ la) * 8;
    const unsigned isf32 = flag[0];
    fx4 acc[4][4];
#pragma unroll
    for (int a = 0; a < 4; ++a)
#pragma unroll
        for (int b = 0; b < 4; ++b) acc[a][b] = (fx4){0.f, 0.f, 0.f, 0.f};

    for (int k0 = 0; k0 < DMODEL; k0 += 64) {
        __syncthreads();
#pragma unroll
        for (int jj = 0; jj < 4; ++jj) {
            int rb = wave * 32 + jj * 8;
            gload16(Xs + rb * 64, Y + (size_t)(i0 + rb + la) * DMODEL + k0 + sc);
            gload16(Ws + rb * 64, WT + (size_t)(j0 + rb + la) * DMODEL + k0 + sc);
        }
        __syncthreads();
#pragma unroll
        for (int ks = 0; ks < 2; ++ks) {
            const int po = ((ks * 4 + lq) ^ sw) * 8;
            bh8 xf[4], wf[4];
#pragma unroll
            for (int im = 0; im < 4; ++im)
                xf[im] = *(const bh8*)(Xs + (wrow + im * 16 + lm) * 64 + po);
#pragma unroll
            for (int in = 0; in < 4; ++in)
                wf[in] = *(const bh8*)(Ws + (wcol + in * 16 + lm) * 64 + po);
#pragma unroll
            for (int im = 0; im < 4; ++im)
#pragma unroll
                for (int in = 0; in < 4; ++in)
                    acc[im][in] = mfma16(wf[in], xf[im], acc[im][in]);
        }
    }
#pragma unroll
    for (int im = 0; im < 4; ++im) {
        int m = i0 + wrow + im * 16 + lm;
#pragma unroll
        for (int in = 0; in < 4; ++in) {
            int nn = j0 + wcol + in * 16 + (lq << 2);
            ushort4 b4 = *(const ushort4*)(Bias + nn);
            ushort4 x4 = *(const ushort4*)(X + (size_t)m * DMODEL + nn);
            float c0 = acc[im][in][0] + bf2f(b4.x) + bf2f(x4.x);
            float c1 = acc[im][in][1] + bf2f(b4.y) + bf2f(x4.y);
            float c2 = acc[im][in][2] + bf2f(b4.z) + bf2f(x4.z);
            float c3 = acc[im][in][3] + bf2f(b4.w) + bf2f(x4.w);
            if (isf32) {
                *(float4*)((float*)Out + (size_t)m * DMODEL + nn) = make_float4(c0, c1, c2, c3);
            } else {
                ushort4 o;
                o.x = f2bf(c0); o.y = f2bf(c1); o.z = f2bf(c2); o.w = f2bf(c3);
                *(ushort4*)((u16*)Out + (size_t)m * DMODEL + nn) = o;
            }
        }
    }
}

extern "C" void kernel_launch(void* const* d_in, const int* in_sizes, int n_in,
                              void* d_out, int out_size, void* d_ws, size_t ws_size,
                              hipStream_t stream)
{
    (void)in_sizes; (void)n_in; (void)out_size; (void)ws_size;
    char* ws = (char*)d_ws;
    u16*   Xc    = (u16*)(ws + 0);            // 33,554,432
    u16*   WqkvT = (u16*)(ws + 33554432);     //  1,572,864
    u16*   WoutT = (u16*)(ws + 35127296);     //    524,288
    u16*   Boutc = (u16*)(ws + 35651584);     //      1,024
    u16*   CWc   = (u16*)(ws + 35652608);     //      1,024
    u16*   Qb    = (u16*)(ws + 35653632);     // 33,554,432  [bh][n][d]
    u16*   Kb    = (u16*)(ws + 69208064);     // 33,554,432  [bh][n][d]; dead after attn3v
    u16*   RT    = (u16*)(ws + 69208064);     // overlays Kb: conv residual [bh*64+d][n]
    u16*   VTb   = (u16*)(ws + 102762496);    // 33,554,432  [bh][d][n]
    float* QL    = (float*)(ws + 136316928);  //  2,097,152
    float* KL    = (float*)(ws + 138414080);  //  2,097,152
    u16*   QLb   = (u16*)(ws + 140511232);    //  1,048,576
    u16*   KLb   = (u16*)(ws + 141559808);    //  1,048,576
    u16*   W3VT  = (u16*)(ws + 142608384);    //  1,048,576  [bh][64][256]
    u16*   WMT   = (u16*)(ws + 143656960);    //  1,048,576  [bh][64][256]
    u16*   A2b   = (u16*)(ws + 144705536);    //  4,194,304
    u16*   zA    = (u16*)(ws + 148899840);    //  4,194,304
    u16*   zAT   = (u16*)(ws + 153094144);    //  4,194,304
    float* A2    = (float*)(ws + 157288448);  // overlay: fp32 A2, then PO/ML, then Yb
    u16*   PO    = (u16*)(ws + 157288448);
    float* ML    = (float*)(ws + 174065664);
    u16*   zB    = (u16*)(ws + 165677056);
    u16*   zBT   = (u16*)(ws + 169871360);
    u16*   xz    = (u16*)(ws + 174065664);
    u16*   xzT   = (u16*)(ws + 178259968);
    u16*   t2T   = (u16*)(ws + 182454272);
    u16*   t3T   = (u16*)(ws + 186648576);
    u16*   Yb    = (u16*)(ws + 157288448);
    unsigned* SCAL = (unsigned*)(ws + 190842880);

    detect_kernel<<<1, 256, 0, stream>>>((const u16*)d_in[0], SCAL + 2);
    convert_kernel<<<65536, 256, 0, stream>>>(d_in[0], Xc, 16777216, SCAL + 2);
    wtrans_kernel<<<3072, 256, 0, stream>>>(d_in[1], WqkvT, 512, 1536, SCAL + 2);
    wtrans_kernel<<<1024, 256, 0, stream>>>(d_in[2], WoutT, 512, 512, SCAL + 2);
    convert_kernel<<<2, 256, 0, stream>>>(d_in[3], Boutc, 512, SCAL + 2);
    convert_kernel<<<2, 256, 0, stream>>>(d_in[4], CWc, 264, SCAL + 2);

    qkv_mfma_kernel<<<dim3(256, 12), 256, 0, stream>>>(Xc, WqkvT, Qb, Kb, VTb);
    pool_kernel<<<dim3(256, BH), 64, 0, stream>>>(Qb, Kb, QL, KL, QLb, KLb);
    attn2_kernel<<<dim3(256, BH), 256, 0, stream>>>(QL, KL, A2);
    init_scal_kernel<<<1, 64, 0, stream>>>(SCAL);
    absmax_kernel<<<32, 256, 0, stream>>>(A2, SCAL);
    z0_kernel<<<8192, 256, 0, stream>>>(A2, SCAL, zA, zAT);
    f2b_kernel<<<8192, 256, 0, stream>>>(A2, A2b, 2097152);

    // flash attn3@v (overwrites A2 region -> PO/ML), combine, then conv into Kb slot
    attn3v_mfma_kernel<<<dim3(8, 4, BH), 256, 0, stream>>>(QLb, Kb, VTb, PO, ML);
    combine_kernel<<<dim3(256, BH), 64, 0, stream>>>(PO, ML, W3VT);
    conv_kernel<<<dim3(4, 2048), 256, 0, stream>>>(VTb, CWc, RT);

    u16 *z = zA, *zT = zAT, *zn = zB, *znT = zBT;
    for (int it = 0; it < 6; ++it) {
        bgemm_mfma_kernel<<<dim3(4, 4, 32), 256, 0, stream>>>(
            A2b, zT, xz, xzT, A2b, 256, 65536, 65536, 65536, 0.f, 0.f, 1.f, 1, 1);
        bgemm_mfma_kernel<<<dim3(4, 4, 32), 256, 0, stream>>>(
            xz, xzT, xz, t2T, xz, 256, 65536, 65536, 65536, 15.f, -7.f, 1.f, 0, 1);
        bgemm_mfma_kernel<<<dim3(4, 4, 32), 256, 0, stream>>>(
            xz, t2T, xz, t3T, xz, 256, 65536, 65536, 65536, 13.f, 0.f, -1.f, 0, 1);
        bgemm_mfma_kernel<<<dim3(4, 4, 32), 256, 0, stream>>>(
            z, t3T, zn, znT, xz, 256, 65536, 65536, 65536, 0.f, 0.f, 0.25f, 1, 1);
        u16* t;
        t = z; z = zn; zn = t;
        t = zT; zT = znT; znT = t;
    }
    // WM^T = (z @ w3v)^T -> [bh][64][256]
    bgemm_mfma_kernel<<<dim3(4, 1, 32), 256, 0, stream>>>(
        z, W3VT, WMT, WMT, xz, 64, 16384, 16384, 16384, 0.f, 0.f, 1.f, 0, 1);
    // y = softmax(q k_l^T) @ WM + conv residual (RT)
    outheads_mfma_kernel<<<dim3(128, BH), 256, 0, stream>>>(Qb, KLb, WMT, RT, Yb);
    // out = x + y @ w_out + b_out
    final_mfma_kernel<<<dim3(256, 4), 256, 0, stream>>>(Yb, WoutT, Boutc, Xc, d_out, SCAL + 2);
}

// Round 6
// 720.846 us; speedup vs baseline: 5.5057x; 1.1225x over previous
//
#include <hip/hip_runtime.h>

// Nystrom attention, MI355X round 6: fetch-once attn3v (K/VT LDS-shared across
// waves), K64-chunk pinv bgemm, vectorized converts.
// b=4, n=8192, dim=512, h=8, dh=64, m=256 landmarks, pinv iters=6, conv k=33.

#define N_SEQ 8192
#define DMODEL 512
#define NHEAD 8
#define DHEAD 64
#define NLAND 256
#define BH 32

typedef unsigned short u16;
typedef __attribute__((ext_vector_type(8))) short bh8;
typedef __attribute__((ext_vector_type(4))) float fx4;

__device__ __forceinline__ float bf2f(u16 u) { return __uint_as_float(((unsigned)u) << 16); }
__device__ __forceinline__ u16 f2bf(float f) {
    unsigned x = __float_as_uint(f);
    return (u16)((x + 0x7fffu + ((x >> 16) & 1u)) >> 16);
}
__device__ __forceinline__ fx4 mfma16(bh8 a, bh8 b, fx4 c) {
    return __builtin_amdgcn_mfma_f32_16x16x32_bf16(a, b, c, 0, 0, 0);
}
__device__ __forceinline__ void gload16(u16* lds, const u16* g) {
    __builtin_amdgcn_global_load_lds(
        (const __attribute__((address_space(1))) unsigned int*)g,
        (__attribute__((address_space(3))) unsigned int*)lds, 16, 0, 0);
}

// ---------------- dtype probe -----------------------------------------------------
__global__ void detect_kernel(const u16* __restrict__ X, unsigned* flag_out)
{
    __shared__ int cnt;
    if (threadIdx.x == 0) cnt = 0;
    __syncthreads();
    u16 u = X[threadIdx.x * 2];
    int e = (u >> 7) & 0xFF;
    int insane = (u != 0) && (e < 90 || e > 140);
    atomicAdd(&cnt, insane);
    __syncthreads();
    if (threadIdx.x == 0) flag_out[0] = (cnt > 64) ? 1u : 0u;
}

// vectorized convert: n4 = elements/4 (all our sizes are /4)
__global__ __launch_bounds__(256) void convert4_kernel(
    const void* __restrict__ in, u16* __restrict__ out, int n4, const unsigned* __restrict__ flag)
{
    int i = blockIdx.x * 256 + threadIdx.x;
    if (i >= n4) return;
    if (flag[0]) {
        float4 v = ((const float4*)in)[i];
        ushort4 o;
        o.x = f2bf(v.x); o.y = f2bf(v.y); o.z = f2bf(v.z); o.w = f2bf(v.w);
        ((ushort4*)out)[i] = o;
    } else {
        ((ushort4*)out)[i] = ((const ushort4*)in)[i];
    }
}

__global__ __launch_bounds__(256) void wtrans_kernel(
    const void* __restrict__ in, u16* __restrict__ out, int rows, int cols,
    const unsigned* __restrict__ flag)
{
    int idx = blockIdx.x * 256 + threadIdx.x;
    if (idx >= rows * cols) return;
    int r = idx / cols, c = idx % cols;
    float v = flag[0] ? ((const float*)in)[idx] : bf2f(((const u16*)in)[idx]);
    out[(size_t)c * rows + r] = f2bf(v);
}

// ---------------- QKV MFMA GEMM (async staging + xor swizzle) ---------------------
__global__ __launch_bounds__(256) void qkv_mfma_kernel(
    const u16* __restrict__ X, const u16* __restrict__ WT,
    u16* __restrict__ Q, u16* __restrict__ K, u16* __restrict__ VT)
{
    __shared__ u16 Xs[128 * 64];
    __shared__ u16 Ws[128 * 64];
    const int tid = threadIdx.x;
    const int wave = tid >> 6, lane = tid & 63;
    const int wrow = (wave >> 1) * 64, wcol = (wave & 1) * 64;
    const int i0 = blockIdx.x * 128;
    const int j0 = blockIdx.y * 128;
    const int la = lane >> 3, lb = lane & 7;
    const int lm = lane & 15, lq = lane >> 4;
    const int sw = lm & 7;
    const int sc = (lb ^ la) * 8;
    fx4 acc[4][4];
#pragma unroll
    for (int a = 0; a < 4; ++a)
#pragma unroll
        for (int b = 0; b < 4; ++b) acc[a][b] = (fx4){0.f, 0.f, 0.f, 0.f};

    for (int k0 = 0; k0 < DMODEL; k0 += 64) {
        __syncthreads();
#pragma unroll
        for (int jj = 0; jj < 4; ++jj) {
            int rb = wave * 32 + jj * 8;
            gload16(Xs + rb * 64, X + (size_t)(i0 + rb + la) * DMODEL + k0 + sc);
            gload16(Ws + rb * 64, WT + (size_t)(j0 + rb + la) * DMODEL + k0 + sc);
        }
        __syncthreads();
#pragma unroll
        for (int ks = 0; ks < 2; ++ks) {
            const int po = ((ks * 4 + lq) ^ sw) * 8;
            bh8 xf[4], wf[4];
#pragma unroll
            for (int im = 0; im < 4; ++im)
                xf[im] = *(const bh8*)(Xs + (wrow + im * 16 + lm) * 64 + po);
#pragma unroll
            for (int in = 0; in < 4; ++in)
                wf[in] = *(const bh8*)(Ws + (wcol + in * 16 + lm) * 64 + po);
#pragma unroll
            for (int im = 0; im < 4; ++im)
#pragma unroll
                for (int in = 0; in < 4; ++in)
                    acc[im][in] = mfma16(wf[in], xf[im], acc[im][in]);
        }
    }
#pragma unroll
    for (int im = 0; im < 4; ++im) {
        int m = i0 + wrow + im * 16 + lm;
        int bb = m >> 13, ns = m & (N_SEQ - 1);
#pragma unroll
        for (int in = 0; in < 4; ++in) {
            int nn = j0 + wcol + in * 16 + (lq << 2);
            int which = nn >> 9;
            int h = (nn >> 6) & 7;
            int d = nn & 63;
            if (which == 2) {
                size_t vb = (size_t)(bb * NHEAD + h) * DHEAD;
#pragma unroll
                for (int cc = 0; cc < 4; ++cc)
                    VT[(vb + d + cc) * N_SEQ + ns] = f2bf(acc[im][in][cc]);
            } else {
                u16* dst = (which == 0) ? Q : K;
                float s = (which == 0) ? 0.125f : 1.f;
                ushort4 o;
                o.x = f2bf(acc[im][in][0] * s); o.y = f2bf(acc[im][in][1] * s);
                o.z = f2bf(acc[im][in][2] * s); o.w = f2bf(acc[im][in][3] * s);
                *(ushort4*)(dst + ((size_t)(bb * NHEAD + h) * N_SEQ + ns) * DHEAD + d) = o;
            }
        }
    }
}

// ---------------- landmark pooling ------------------------------------------------
__global__ __launch_bounds__(64) void pool_kernel(
    const u16* __restrict__ Q, const u16* __restrict__ K,
    float* __restrict__ QL, float* __restrict__ KL,
    u16* __restrict__ QLb, u16* __restrict__ KLb)
{
    int m = blockIdx.x, bh = blockIdx.y, d = threadIdx.x;
    size_t base = ((size_t)bh * N_SEQ + m * 32) * DHEAD + d;
    float sq = 0.f, sk = 0.f;
#pragma unroll
    for (int i = 0; i < 32; ++i) {
        sq += bf2f(Q[base + i * DHEAD]);
        sk += bf2f(K[base + i * DHEAD]);
    }
    size_t ob = ((size_t)bh * NLAND + m) * DHEAD + d;
    sq *= (1.f / 32.f); sk *= (1.f / 32.f);
    QL[ob] = sq; KL[ob] = sk;
    QLb[ob] = f2bf(sq); KLb[ob] = f2bf(sk);
}

// ---------------- attn2 = softmax(q_l @ k_l^T) ------------------------------------
__global__ __launch_bounds__(256) void attn2_kernel(
    const float* __restrict__ QL, const float* __restrict__ KL, float* __restrict__ A2)
{
    __shared__ float qrow[64];
    __shared__ float red[256];
    int i = blockIdx.x, bh = blockIdx.y, j = threadIdx.x;
    if (j < 64) qrow[j] = QL[((size_t)bh * NLAND + i) * DHEAD + j];
    __syncthreads();
    const float* kr = KL + ((size_t)bh * NLAND + j) * DHEAD;
    float lg = 0.f;
#pragma unroll
    for (int d = 0; d < 64; ++d) lg += qrow[d] * kr[d];
    red[j] = lg; __syncthreads();
    for (int s = 128; s > 0; s >>= 1) { if (j < s) red[j] = fmaxf(red[j], red[j + s]); __syncthreads(); }
    float mx = red[0]; __syncthreads();
    float p = __expf(lg - mx);
    red[j] = p; __syncthreads();
    for (int s = 128; s > 0; s >>= 1) { if (j < s) red[j] += red[j + s]; __syncthreads(); }
    float sum = red[0];
    A2[((size_t)bh * NLAND + i) * NLAND + j] = p / sum;
}

__global__ void init_scal_kernel(unsigned* scal) { if (threadIdx.x < 2) scal[threadIdx.x] = 0u; }

__global__ __launch_bounds__(256) void absmax_kernel(const float* __restrict__ A2, unsigned* scal)
{
    __shared__ float red[256];
    int bh = blockIdx.x, t = threadIdx.x;
    const float* Ab = A2 + (size_t)bh * 65536;
    float cs = 0.f, rs = 0.f;
    for (int j = 0; j < 256; ++j) cs += fabsf(Ab[t * 256 + j]);
    for (int i = 0; i < 256; ++i) rs += fabsf(Ab[i * 256 + t]);
    red[t] = cs; __syncthreads();
    for (int s = 128; s > 0; s >>= 1) { if (t < s) red[t] = fmaxf(red[t], red[t + s]); __syncthreads(); }
    if (t == 0) atomicMax(scal + 0, __float_as_uint(red[0]));
    __syncthreads();
    red[t] = rs; __syncthreads();
    for (int s = 128; s > 0; s >>= 1) { if (t < s) red[t] = fmaxf(red[t], red[t + s]); __syncthreads(); }
    if (t == 0) atomicMax(scal + 1, __float_as_uint(red[0]));
}

// z0 + A2->bf16 in one pass
__global__ __launch_bounds__(256) void z0_kernel(
    const float* __restrict__ A2, const unsigned* __restrict__ scal,
    u16* __restrict__ zb, u16* __restrict__ zbT, u16* __restrict__ A2b)
{
    float inv = 1.f / (__uint_as_float(scal[0]) * __uint_as_float(scal[1]));
    size_t idx = (size_t)blockIdx.x * 256 + threadIdx.x;
    size_t bh = idx >> 16;
    int r = (int)(idx & 65535);
    int i = r >> 8, j = r & 255;
    float a = A2[idx];
    zb[idx]  = f2bf(A2[(bh << 16) + (size_t)j * 256 + i] * inv);
    zbT[idx] = f2bf(a * inv);
    A2b[idx] = f2bf(a);
}

// ---------------- batched MFMA GEMM for pinv (K-chunk 64) -------------------------
__global__ __launch_bounds__(256) void bgemm_mfma_kernel(
    const u16* __restrict__ A, const u16* __restrict__ BT,
    u16* __restrict__ Cn, u16* __restrict__ Ct, const u16* __restrict__ E,
    int N, long sB, long sCn, long sCt, float sc, float alpha, float beta, int wn, int wt)
{
    __shared__ u16 As[64 * 72];
    __shared__ u16 Bs[64 * 72];
    const int tid = threadIdx.x;
    const int wave = tid >> 6, lane = tid & 63;
    const int wm = (wave >> 1) * 32, wnn = (wave & 1) * 32;
    const int i0 = blockIdx.x * 64, j0 = blockIdx.y * 64, bh = blockIdx.z;
    const u16* Ab = A + (size_t)bh * 65536;
    const u16* Bb = BT + (size_t)bh * sB;
    const int srow = tid >> 2, scol = (tid & 3) * 16;
    const int lm = lane & 15, lq = lane >> 4;
    fx4 acc[2][2];
#pragma unroll
    for (int a = 0; a < 2; ++a)
#pragma unroll
        for (int b = 0; b < 2; ++b) acc[a][b] = (fx4){0.f, 0.f, 0.f, 0.f};

    for (int k0 = 0; k0 < 256; k0 += 64) {
        uint4 a0 = *(const uint4*)(Ab + (size_t)(i0 + srow) * 256 + k0 + scol);
        uint4 a1 = *(const uint4*)(Ab + (size_t)(i0 + srow) * 256 + k0 + scol + 8);
        uint4 b0 = *(const uint4*)(Bb + (size_t)(j0 + srow) * 256 + k0 + scol);
        uint4 b1 = *(const uint4*)(Bb + (size_t)(j0 + srow) * 256 + k0 + scol + 8);
        __syncthreads();
        *(uint4*)(As + srow * 72 + scol) = a0;
        *(uint4*)(As + srow * 72 + scol + 8) = a1;
        *(uint4*)(Bs + srow * 72 + scol) = b0;
        *(uint4*)(Bs + srow * 72 + scol + 8) = b1;
        __syncthreads();
#pragma unroll
        for (int ks = 0; ks < 2; ++ks) {
            bh8 lf[2], rf[2];
#pragma unroll
            for (int im = 0; im < 2; ++im)
                lf[im] = *(const bh8*)(As + (wm + im * 16 + lm) * 72 + ks * 32 + lq * 8);
#pragma unroll
            for (int in = 0; in < 2; ++in)
                rf[in] = *(const bh8*)(Bs + (wnn + in * 16 + lm) * 72 + ks * 32 + lq * 8);
#pragma unroll
            for (int im = 0; im < 2; ++im)
#pragma unroll
                for (int in = 0; in < 2; ++in)
                    acc[im][in] = mfma16(lf[im], rf[in], acc[im][in]);
        }
    }
#pragma unroll
    for (int im = 0; im < 2; ++im) {
#pragma unroll
        for (int in = 0; in < 2; ++in) {
            int n = j0 + wnn + in * 16 + lm;
            int m0 = i0 + wm + im * 16 + (lq << 2);
            float c[4];
#pragma unroll
            for (int r = 0; r < 4; ++r) {
                int m = m0 + r;
                float x = beta * acc[im][in][r];
                if (alpha != 0.f)
                    x += alpha * bf2f(E[(size_t)bh * 65536 + (size_t)m * 256 + n]);
                if (m == n) x += sc;
                c[r] = x;
            }
            if (wn) {
#pragma unroll
                for (int r = 0; r < 4; ++r)
                    Cn[(size_t)bh * sCn + (size_t)(m0 + r) * N + n] = f2bf(c[r]);
            }
            if (wt) {
                ushort4 o;
                o.x = f2bf(c[0]); o.y = f2bf(c[1]); o.z = f2bf(c[2]); o.w = f2bf(c[3]);
                *(ushort4*)(Ct + (size_t)bh * sCt + (size_t)n * 256 + m0) = o;
            }
        }
    }
}

// ---------------- attn3@v flash MFMA: fetch-once, 4 waves share K/VT chunks -------
// grid (16 nparts, 32 bh); wave w handles m = w*64..w*64+63 over its 512-n slice.
__global__ __launch_bounds__(256, 2) void attn3v_mfma_kernel(
    const u16* __restrict__ QLb, const u16* __restrict__ Kb,
    const u16* __restrict__ VTb, u16* __restrict__ PO, float* __restrict__ ML)
{
    __shared__ u16 Ks[64 * 72];
    __shared__ u16 Vs[64 * 72];
    __shared__ u16 Pw[4][64 * 72];
    const int tid = threadIdx.x;
    const int wave = tid >> 6, lane = tid & 63;
    const int q = lane >> 4, l15 = lane & 15;
    const int part = blockIdx.x;
    const int bh = blockIdx.y;
    const int nbase = part * 512;
    const int srow = tid >> 2, scol = (tid & 3) * 16;
    u16* Pp = Pw[wave];
    bh8 qf[4][2];
#pragma unroll
    for (int mt = 0; mt < 4; ++mt)
#pragma unroll
        for (int ks = 0; ks < 2; ++ks)
            qf[mt][ks] = *(const bh8*)(QLb + ((size_t)bh * NLAND + wave * 64 + mt * 16 + l15) * DHEAD + ks * 32 + q * 8);
    float M[4] = {-1e30f, -1e30f, -1e30f, -1e30f};
    float L[4] = {0.f, 0.f, 0.f, 0.f};
    fx4 O[4][4];
#pragma unroll
    for (int mt = 0; mt < 4; ++mt)
#pragma unroll
        for (int dt = 0; dt < 4; ++dt) O[mt][dt] = (fx4){0.f, 0.f, 0.f, 0.f};

    for (int c = 0; c < 8; ++c) {
        const int n0 = nbase + c * 64;
        uint4 k0v = *(const uint4*)(Kb + ((size_t)bh * N_SEQ + n0 + srow) * DHEAD + scol);
        uint4 k1v = *(const uint4*)(Kb + ((size_t)bh * N_SEQ + n0 + srow) * DHEAD + scol + 8);
        uint4 v0v = *(const uint4*)(VTb + ((size_t)bh * DHEAD + srow) * N_SEQ + n0 + scol);
        uint4 v1v = *(const uint4*)(VTb + ((size_t)bh * DHEAD + srow) * N_SEQ + n0 + scol + 8);
        __syncthreads();
        *(uint4*)(Ks + srow * 72 + scol) = k0v;
        *(uint4*)(Ks + srow * 72 + scol + 8) = k1v;
        *(uint4*)(Vs + srow * 72 + scol) = v0v;
        *(uint4*)(Vs + srow * 72 + scol + 8) = v1v;
        __syncthreads();
        fx4 S[4][4];   // [nt][mt]
#pragma unroll
        for (int nt = 0; nt < 4; ++nt)
#pragma unroll
            for (int mt = 0; mt < 4; ++mt) S[nt][mt] = (fx4){0.f, 0.f, 0.f, 0.f};
#pragma unroll
        for (int ks = 0; ks < 2; ++ks) {
            bh8 kf[4];
#pragma unroll
            for (int nt = 0; nt < 4; ++nt)
                kf[nt] = *(const bh8*)(Ks + (nt * 16 + l15) * 72 + ks * 32 + q * 8);
#pragma unroll
            for (int nt = 0; nt < 4; ++nt)
#pragma unroll
                for (int mt = 0; mt < 4; ++mt)
                    S[nt][mt] = mfma16(kf[nt], qf[mt][ks], S[nt][mt]);   // D[n][m]
        }
#pragma unroll
        for (int mt = 0; mt < 4; ++mt) {
            float cm = -1e30f;
#pragma unroll
            for (int nt = 0; nt < 4; ++nt)
#pragma unroll
                for (int r = 0; r < 4; ++r) cm = fmaxf(cm, S[nt][mt][r]);
            cm = fmaxf(cm, __shfl_xor(cm, 16));
            cm = fmaxf(cm, __shfl_xor(cm, 32));
            float Mn = fmaxf(M[mt], cm);
            float al = __expf(M[mt] - Mn);
            M[mt] = Mn;
            L[mt] *= al;
#pragma unroll
            for (int dt = 0; dt < 4; ++dt) {
                O[mt][dt][0] *= al; O[mt][dt][1] *= al;
                O[mt][dt][2] *= al; O[mt][dt][3] *= al;
            }
            float ps = 0.f;
#pragma unroll
            for (int nt = 0; nt < 4; ++nt)
#pragma unroll
                for (int r = 0; r < 4; ++r) {
                    float p = __expf(S[nt][mt][r] - Mn);
                    ps += p;
                    Pp[(mt * 16 + l15) * 72 + nt * 16 + q * 4 + r] = f2bf(p);
                }
            ps += __shfl_xor(ps, 16);
            ps += __shfl_xor(ps, 32);
            L[mt] += ps;
        }
#pragma unroll
        for (int ks = 0; ks < 2; ++ks) {
            bh8 pf[4];
#pragma unroll
            for (int mt = 0; mt < 4; ++mt)
                pf[mt] = *(const bh8*)(Pp + (mt * 16 + l15) * 72 + ks * 32 + q * 8);
#pragma unroll
            for (int dt = 0; dt < 4; ++dt) {
                bh8 vf = *(const bh8*)(Vs + (dt * 16 + l15) * 72 + ks * 32 + q * 8);
#pragma unroll
                for (int mt = 0; mt < 4; ++mt)
                    O[mt][dt] = mfma16(vf, pf[mt], O[mt][dt]);   // D[d][m]
            }
        }
    }
#pragma unroll
    for (int mt = 0; mt < 4; ++mt) {
        size_t mrow = (size_t)(bh * 16 + part) * NLAND + wave * 64 + mt * 16 + l15;
#pragma unroll
        for (int dt = 0; dt < 4; ++dt) {
            ushort4 o;
            o.x = f2bf(O[mt][dt][0]); o.y = f2bf(O[mt][dt][1]);
            o.z = f2bf(O[mt][dt][2]); o.w = f2bf(O[mt][dt][3]);
            *(ushort4*)(PO + mrow * DHEAD + dt * 16 + q * 4) = o;
        }
        if (q == 0) { ML[mrow * 2] = M[mt]; ML[mrow * 2 + 1] = L[mt]; }
    }
}

__global__ __launch_bounds__(64) void combine_kernel(
    const u16* __restrict__ PO, const float* __restrict__ ML, u16* __restrict__ W3VT)
{
    int m = blockIdx.x, bh = blockIdx.y, d = threadIdx.x;
    float Mg = -1e30f;
#pragma unroll
    for (int p = 0; p < 16; ++p)
        Mg = fmaxf(Mg, ML[((size_t)(bh * 16 + p) * NLAND + m) * 2]);
    float denom = 0.f, o = 0.f;
#pragma unroll
    for (int p = 0; p < 16; ++p) {
        size_t ix = (size_t)(bh * 16 + p) * NLAND + m;
        float w = __expf(ML[ix * 2] - Mg);
        denom += ML[ix * 2 + 1] * w;
        o += bf2f(PO[ix * DHEAD + d]) * w;
    }
    W3VT[((size_t)bh * DHEAD + d) * NLAND + m] = f2bf(o / denom);
}

// ---------------- depthwise conv residual: RT[bh*64+d][n] from VT -----------------
__global__ __launch_bounds__(256) void conv_kernel(
    const u16* __restrict__ VT, const u16* __restrict__ CW, u16* __restrict__ RT)
{
    __shared__ float vl[2080];
    __shared__ float cws[33];
    const int tid = threadIdx.x;
    const int c0 = blockIdx.x * 2048;
    const int row = blockIdx.y;
    const int h = (row >> 6) & 7;
    const u16* src = VT + (size_t)row * N_SEQ;
    for (int i = tid; i < 2080; i += 256) {
        int gn = c0 - 16 + i;
        vl[i] = (gn >= 0 && gn < N_SEQ) ? bf2f(src[gn]) : 0.f;
    }
    if (tid < 33) cws[tid] = bf2f(CW[h * 33 + tid]);
    __syncthreads();
    float v[40];
    const int base = tid * 8;
#pragma unroll
    for (int i = 0; i < 40; ++i) v[i] = vl[base + i];
    float s[8];
#pragma unroll
    for (int j = 0; j < 8; ++j) {
        float a = 0.f;
#pragma unroll
        for (int t = 0; t < 33; ++t) a += cws[t] * v[j + t];
        s[j] = a;
    }
    u16* dst = RT + (size_t)row * N_SEQ + c0 + base;
    ushort4 o0, o1;
    o0.x = f2bf(s[0]); o0.y = f2bf(s[1]); o0.z = f2bf(s[2]); o0.w = f2bf(s[3]);
    o1.x = f2bf(s[4]); o1.y = f2bf(s[5]); o1.z = f2bf(s[6]); o1.w = f2bf(s[7]);
    *(ushort4*)dst = o0;
    *(ushort4*)(dst + 4) = o1;
}

// ---------------- outheads: attn1 softmax + @WM + RT residual, 64 n/block ---------
__global__ __launch_bounds__(256) void outheads_mfma_kernel(
    const u16* __restrict__ Qb, const u16* __restrict__ KLb,
    const u16* __restrict__ WMT, const u16* __restrict__ RT,
    u16* __restrict__ Y)
{
    __shared__ u16 Pl[64 * 264];
    __shared__ float wmax[4][64];
    __shared__ float wsum[4][64];
    const int tid = threadIdx.x;
    const int wave = tid >> 6, lane = tid & 63;
    const int q = lane >> 4, l15 = lane & 15;
    const int bh = blockIdx.y;
    const int bb = bh >> 3, h = bh & 7;
    const int n0 = blockIdx.x * 64;
    fx4 S[4][4];
#pragma unroll
    for (int a = 0; a < 4; ++a)
#pragma unroll
        for (int b = 0; b < 4; ++b) S[a][b] = (fx4){0.f, 0.f, 0.f, 0.f};
#pragma unroll
    for (int ks = 0; ks < 2; ++ks) {
        bh8 qfr[4];
#pragma unroll
        for (int nt = 0; nt < 4; ++nt)
            qfr[nt] = *(const bh8*)(Qb + ((size_t)bh * N_SEQ + n0 + nt * 16 + l15) * DHEAD + ks * 32 + q * 8);
#pragma unroll
        for (int mt = 0; mt < 4; ++mt) {
            bh8 kf = *(const bh8*)(KLb + ((size_t)bh * NLAND + wave * 64 + mt * 16 + l15) * DHEAD + ks * 32 + q * 8);
#pragma unroll
            for (int nt = 0; nt < 4; ++nt)
                S[nt][mt] = mfma16(qfr[nt], kf, S[nt][mt]);
        }
    }
#pragma unroll
    for (int nt = 0; nt < 4; ++nt)
#pragma unroll
        for (int r = 0; r < 4; ++r) {
            float pm = fmaxf(fmaxf(S[nt][0][r], S[nt][1][r]), fmaxf(S[nt][2][r], S[nt][3][r]));
            pm = fmaxf(pm, __shfl_xor(pm, 1));
            pm = fmaxf(pm, __shfl_xor(pm, 2));
            pm = fmaxf(pm, __shfl_xor(pm, 4));
            pm = fmaxf(pm, __shfl_xor(pm, 8));
            if (l15 == 0) wmax[wave][nt * 16 + q * 4 + r] = pm;
        }
    __syncthreads();
#pragma unroll
    for (int nt = 0; nt < 4; ++nt)
#pragma unroll
        for (int r = 0; r < 4; ++r) {
            int nl = nt * 16 + q * 4 + r;
            float Mf = fmaxf(fmaxf(wmax[0][nl], wmax[1][nl]), fmaxf(wmax[2][nl], wmax[3][nl]));
            float ps = 0.f;
#pragma unroll
            for (int mt = 0; mt < 4; ++mt) {
                float p = __expf(S[nt][mt][r] - Mf);
                ps += p;
                Pl[nl * 264 + wave * 64 + mt * 16 + l15] = f2bf(p);
            }
            ps += __shfl_xor(ps, 1);
            ps += __shfl_xor(ps, 2);
            ps += __shfl_xor(ps, 4);
            ps += __shfl_xor(ps, 8);
            if (l15 == 0) wsum[wave][nl] = ps;
        }
    __syncthreads();
    fx4 O[4];
#pragma unroll
    for (int nt = 0; nt < 4; ++nt) O[nt] = (fx4){0.f, 0.f, 0.f, 0.f};
#pragma unroll
    for (int ks = 0; ks < 8; ++ks) {
        bh8 af = *(const bh8*)(WMT + ((size_t)bh * DHEAD + wave * 16 + l15) * NLAND + ks * 32 + q * 8);
#pragma unroll
        for (int nt = 0; nt < 4; ++nt) {
            bh8 pf = *(const bh8*)(Pl + (size_t)(nt * 16 + l15) * 264 + ks * 32 + q * 8);
            O[nt] = mfma16(af, pf, O[nt]);
        }
    }
#pragma unroll
    for (int nt = 0; nt < 4; ++nt) {
        int nl = nt * 16 + l15;
        float inv = 1.f / (wsum[0][nl] + wsum[1][nl] + wsum[2][nl] + wsum[3][nl]);
        int d0 = wave * 16 + (q << 2);
        fx4 v = O[nt];
#pragma unroll
        for (int c = 0; c < 4; ++c)
            v[c] = v[c] * inv + bf2f(RT[(size_t)(bh * DHEAD + d0 + c) * N_SEQ + n0 + nl]);
        ushort4 o;
        o.x = f2bf(v[0]); o.y = f2bf(v[1]); o.z = f2bf(v[2]); o.w = f2bf(v[3]);
        *(ushort4*)(Y + ((size_t)bb * N_SEQ + n0 + nl) * DMODEL + h * DHEAD + d0) = o;
    }
}

// ---------------- final MFMA GEMM (async staging + swizzle) -----------------------
__global__ __launch_bounds__(256) void final_mfma_kernel(
    const u16* __restrict__ Y, const u16* __restrict__ WT,
    const u16* __restrict__ Bias, const u16* __restrict__ X, void* __restrict__ Out,
    const unsigned* __restrict__ flag)
{
    __shared__ u16 Xs[128 * 64];
    __shared__ u16 Ws[128 * 64];
    const int tid = threadIdx.x;
    const int wave = tid >> 6, lane = tid & 63;
    const int wrow = (wave >> 1) * 64, wcol = (wave & 1) * 64;
    const int i0 = blockIdx.x * 128;
    const int j0 = blockIdx.y * 128;
    const int la = lane >> 3, lb = lane & 7;
    const int lm = lane & 15, lq = lane >> 4;
    const int sw = lm & 7;
    const int sc = (lb ^ la) * 8;
    const unsigned isf32 = flag[0];
    fx4 acc[4][4];
#pragma unroll
    for (int a = 0; a < 4; ++a)
#pragma unroll
        for (int b = 0; b < 4; ++b) acc[a][b] = (fx4){0.f, 0.f, 0.f, 0.f};

    for (int k0 = 0; k0 < DMODEL; k0 += 64) {
        __syncthreads();
#pragma unroll
        for (int jj = 0; jj < 4; ++jj) {
            int rb = wave * 32 + jj * 8;
            gload16(Xs + rb * 64, Y + (size_t)(i0 + rb + la) * DMODEL + k0 + sc);
            gload16(Ws + rb * 64, WT + (size_t)(j0 + rb + la) * DMODEL + k0 + sc);
        }
        __syncthreads();
#pragma unroll
        for (int ks = 0; ks < 2; ++ks) {
            const int po = ((ks * 4 + lq) ^ sw) * 8;
            bh8 xf[4], wf[4];
#pragma unroll
            for (int im = 0; im < 4; ++im)
                xf[im] = *(const bh8*)(Xs + (wrow + im * 16 + lm) * 64 + po);
#pragma unroll
            for (int in = 0; in < 4; ++in)
                wf[in] = *(const bh8*)(Ws + (wcol + in * 16 + lm) * 64 + po);
#pragma unroll
            for (int im = 0; im < 4; ++im)
#pragma unroll
                for (int in = 0; in < 4; ++in)
                    acc[im][in] = mfma16(wf[in], xf[im], acc[im][in]);
        }
    }
#pragma unroll
    for (int im = 0; im < 4; ++im) {
        int m = i0 + wrow + im * 16 + lm;
#pragma unroll
        for (int in = 0; in < 4; ++in) {
            int nn = j0 + wcol + in * 16 + (lq << 2);
            ushort4 b4 = *(const ushort4*)(Bias + nn);
            ushort4 x4 = *(const ushort4*)(X + (size_t)m * DMODEL + nn);
            float c0 = acc[im][in][0] + bf2f(b4.x) + bf2f(x4.x);
            float c1 = acc[im][in][1] + bf2f(b4.y) + bf2f(x4.y);
            float c2 = acc[im][in][2] + bf2f(b4.z) + bf2f(x4.z);
            float c3 = acc[im][in][3] + bf2f(b4.w) + bf2f(x4.w);
            if (isf32) {
                *(float4*)((float*)Out + (size_t)m * DMODEL + nn) = make_float4(c0, c1, c2, c3);
            } else {
                ushort4 o;
                o.x = f2bf(c0); o.y = f2bf(c1); o.z = f2bf(c2); o.w = f2bf(c3);
                *(ushort4*)((u16*)Out + (size_t)m * DMODEL + nn) = o;
            }
        }
    }
}

extern "C" void kernel_launch(void* const* d_in, const int* in_sizes, int n_in,
                              void* d_out, int out_size, void* d_ws, size_t ws_size,
                              hipStream_t stream)
{
    (void)in_sizes; (void)n_in; (void)out_size; (void)ws_size;
    char* ws = (char*)d_ws;
    u16*   Xc    = (u16*)(ws + 0);            // 33,554,432
    u16*   WqkvT = (u16*)(ws + 33554432);     //  1,572,864
    u16*   WoutT = (u16*)(ws + 35127296);     //    524,288
    u16*   Boutc = (u16*)(ws + 35651584);     //      1,024
    u16*   CWc   = (u16*)(ws + 35652608);     //      1,024
    u16*   Qb    = (u16*)(ws + 35653632);     // 33,554,432  [bh][n][d]
    u16*   Kb    = (u16*)(ws + 69208064);     // 33,554,432  [bh][n][d]; dead after attn3v
    u16*   RT    = (u16*)(ws + 69208064);     // overlays Kb post-attn3v
    u16*   VTb   = (u16*)(ws + 102762496);    // 33,554,432  [bh][d][n]
    float* QL    = (float*)(ws + 136316928);  //  2,097,152
    float* KL    = (float*)(ws + 138414080);  //  2,097,152
    u16*   QLb   = (u16*)(ws + 140511232);    //  1,048,576
    u16*   KLb   = (u16*)(ws + 141559808);    //  1,048,576
    u16*   W3VT  = (u16*)(ws + 142608384);    //  1,048,576
    u16*   WMT   = (u16*)(ws + 143656960);    //  1,048,576
    u16*   A2b   = (u16*)(ws + 144705536);    //  4,194,304
    u16*   zA    = (u16*)(ws + 148899840);    //  4,194,304
    u16*   zAT   = (u16*)(ws + 153094144);    //  4,194,304
    float* A2    = (float*)(ws + 157288448);  // overlay region
    u16*   PO    = (u16*)(ws + 157288448);
    float* ML    = (float*)(ws + 174065664);
    u16*   zB    = (u16*)(ws + 165677056);
    u16*   zBT   = (u16*)(ws + 169871360);
    u16*   xz    = (u16*)(ws + 174065664);
    u16*   xzT   = (u16*)(ws + 178259968);
    u16*   t2T   = (u16*)(ws + 182454272);
    u16*   t3T   = (u16*)(ws + 186648576);
    u16*   Yb    = (u16*)(ws + 157288448);
    unsigned* SCAL = (unsigned*)(ws + 190842880);

    detect_kernel<<<1, 256, 0, stream>>>((const u16*)d_in[0], SCAL + 2);
    convert4_kernel<<<16384, 256, 0, stream>>>(d_in[0], Xc, 4194304, SCAL + 2);
    wtrans_kernel<<<3072, 256, 0, stream>>>(d_in[1], WqkvT, 512, 1536, SCAL + 2);
    wtrans_kernel<<<1024, 256, 0, stream>>>(d_in[2], WoutT, 512, 512, SCAL + 2);
    convert4_kernel<<<1, 256, 0, stream>>>(d_in[3], Boutc, 128, SCAL + 2);
    convert4_kernel<<<1, 256, 0, stream>>>(d_in[4], CWc, 66, SCAL + 2);

    qkv_mfma_kernel<<<dim3(256, 12), 256, 0, stream>>>(Xc, WqkvT, Qb, Kb, VTb);
    pool_kernel<<<dim3(256, BH), 64, 0, stream>>>(Qb, Kb, QL, KL, QLb, KLb);
    attn2_kernel<<<dim3(256, BH), 256, 0, stream>>>(QL, KL, A2);
    init_scal_kernel<<<1, 64, 0, stream>>>(SCAL);
    absmax_kernel<<<32, 256, 0, stream>>>(A2, SCAL);
    z0_kernel<<<8192, 256, 0, stream>>>(A2, SCAL, zA, zAT, A2b);

    // flash attn3@v (fetch-once), combine, conv into Kb slot
    attn3v_mfma_kernel<<<dim3(16, BH), 256, 0, stream>>>(QLb, Kb, VTb, PO, ML);
    combine_kernel<<<dim3(256, BH), 64, 0, stream>>>(PO, ML, W3VT);
    conv_kernel<<<dim3(4, 2048), 256, 0, stream>>>(VTb, CWc, RT);

    u16 *z = zA, *zT = zAT, *zn = zB, *znT = zBT;
    for (int it = 0; it < 6; ++it) {
        bgemm_mfma_kernel<<<dim3(4, 4, 32), 256, 0, stream>>>(
            A2b, zT, xz, xzT, A2b, 256, 65536, 65536, 65536, 0.f, 0.f, 1.f, 1, 1);
        bgemm_mfma_kernel<<<dim3(4, 4, 32), 256, 0, stream>>>(
            xz, xzT, xz, t2T, xz, 256, 65536, 65536, 65536, 15.f, -7.f, 1.f, 0, 1);
        bgemm_mfma_kernel<<<dim3(4, 4, 32), 256, 0, stream>>>(
            xz, t2T, xz, t3T, xz, 256, 65536, 65536, 65536, 13.f, 0.f, -1.f, 0, 1);
        bgemm_mfma_kernel<<<dim3(4, 4, 32), 256, 0, stream>>>(
            z, t3T, zn, znT, xz, 256, 65536, 65536, 65536, 0.f, 0.f, 0.25f, 1, 1);
        u16* t;
        t = z; z = zn; zn = t;
        t = zT; zT = znT; znT = t;
    }
    bgemm_mfma_kernel<<<dim3(4, 1, 32), 256, 0, stream>>>(
        z, W3VT, WMT, WMT, xz, 64, 16384, 16384, 16384, 0.f, 0.f, 1.f, 0, 1);
    outheads_mfma_kernel<<<dim3(128, BH), 256, 0, stream>>>(Qb, KLb, WMT, RT, Yb);
    final_mfma_kernel<<<dim3(256, 4), 256, 0, stream>>>(Yb, WoutT, Boutc, Xc, d_out, SCAL + 2);
}